// Round 1
// baseline (521.181 us; speedup 1.0000x reference)
//
#include <hip/hip_runtime.h>

typedef unsigned short u16;
typedef unsigned int u32;

#define TOKENS 4096   // B*T
#define HDIM 1024
#define IDIM 4096
#define NHEADS 4
#define NKEYS 64
#define TOPK 8
#define QDIM 512      // 2 * NHEADS * 64

typedef __bf16 bf16x8 __attribute__((ext_vector_type(8)));
typedef float  f32x4  __attribute__((ext_vector_type(4)));

__device__ __forceinline__ u16 f2bf(float f) {
    u32 u = __float_as_uint(f);
    u += 0x7fffu + ((u >> 16) & 1u);   // RNE
    return (u16)(u >> 16);
}
__device__ __forceinline__ float bf2f(u16 h) { return __uint_as_float(((u32)h) << 16); }

// fp32 -> bf16 hi (+ optional lo residual) conversion, vectorized
__global__ void cvt_kernel(const float* __restrict__ in, u16* __restrict__ hi,
                           u16* __restrict__ lo, int n4) {
    int i = blockIdx.x * blockDim.x + threadIdx.x;
    if (i >= n4) return;
    float4 v = reinterpret_cast<const float4*>(in)[i];
    float vf[4] = {v.x, v.y, v.z, v.w};
    ushort4 h;
    u16 hh[4];
#pragma unroll
    for (int j = 0; j < 4; j++) hh[j] = f2bf(vf[j]);
    h.x = hh[0]; h.y = hh[1]; h.z = hh[2]; h.w = hh[3];
    reinterpret_cast<ushort4*>(hi)[i] = h;
    if (lo) {
        ushort4 l4;
        u16 ll[4];
#pragma unroll
        for (int j = 0; j < 4; j++) ll[j] = f2bf(vf[j] - bf2f(hh[j]));
        l4.x = ll[0]; l4.y = ll[1]; l4.z = ll[2]; l4.w = ll[3];
        reinterpret_cast<ushort4*>(lo)[i] = l4;
    }
}

__device__ __forceinline__ void gload16(const void* g, void* s) {
    auto gp = reinterpret_cast<const __attribute__((address_space(1))) u32*>(
        reinterpret_cast<uintptr_t>(g));
    auto sp = reinterpret_cast<__attribute__((address_space(3))) u32*>(
        reinterpret_cast<uintptr_t>(s));
    __builtin_amdgcn_global_load_lds(gp, sp, 16, 0, 0);
}

#define BM 128
#define BN 128
#define BK 32

// C[M,N] = A[M,K] * B[N,K]^T   (bf16 in, fp32 accumulate)
// EPI 0: f32 store or += (accumulate flag)   (q projection)
// EPI 1: silu -> bf16 store                  (up proj)
// EPI 2: f32 store of acc + ext[row*N+col]   (down proj + expert states)
template <int EPI>
__global__ __launch_bounds__(256) void gemm_bt(const u16* __restrict__ A,
                                               const u16* __restrict__ B,
                                               void* __restrict__ Cout,
                                               const float* __restrict__ ext,
                                               int M, int N, int K, int accumulate) {
    __shared__ u16 As[BM * BK];
    __shared__ u16 Bs[BN * BK];
    const int t = threadIdx.x;
    const int lane = t & 63;
    const int wave = t >> 6;
    const int wr = wave >> 1, wc = wave & 1;
    const int m0 = blockIdx.y * BM;
    const int n0 = blockIdx.x * BN;

    f32x4 acc[4][4];
#pragma unroll
    for (int i = 0; i < 4; i++)
#pragma unroll
        for (int j = 0; j < 4; j++) acc[i][j] = (f32x4){0.f, 0.f, 0.f, 0.f};

    const size_t krow = (size_t)K * 2;  // bytes per row
    const int ro = lane & 15;
    const int ko = (lane >> 4) * 16;  // byte offset into 64B row

    for (int k0 = 0; k0 < K; k0 += BK) {
#pragma unroll
        for (int rnd = 0; rnd < 2; rnd++) {
            int o = t * 16 + rnd * 4096;
            int row = o >> 6, kb = o & 63;
            gload16((const char*)A + (size_t)(m0 + row) * krow + (size_t)k0 * 2 + kb,
                    (char*)As + o);
            gload16((const char*)B + (size_t)(n0 + row) * krow + (size_t)k0 * 2 + kb,
                    (char*)Bs + o);
        }
        __syncthreads();
        bf16x8 fa[4], fb[4];
#pragma unroll
        for (int i = 0; i < 4; i++) {
            fa[i] = *reinterpret_cast<const bf16x8*>((const char*)As +
                                                     (wr * 64 + i * 16 + ro) * 64 + ko);
            fb[i] = *reinterpret_cast<const bf16x8*>((const char*)Bs +
                                                     (wc * 64 + i * 16 + ro) * 64 + ko);
        }
#pragma unroll
        for (int i = 0; i < 4; i++)
#pragma unroll
            for (int j = 0; j < 4; j++)
                acc[i][j] = __builtin_amdgcn_mfma_f32_16x16x32_bf16(fa[i], fb[j],
                                                                    acc[i][j], 0, 0, 0);
        __syncthreads();
    }

#pragma unroll
    for (int i = 0; i < 4; i++)
#pragma unroll
        for (int j = 0; j < 4; j++) {
            int col = n0 + wc * 64 + j * 16 + (lane & 15);
            int rbase = m0 + wr * 64 + i * 16 + (lane >> 4) * 4;
#pragma unroll
            for (int r = 0; r < 4; r++) {
                int row = rbase + r;
                float v = acc[i][j][r];
                size_t off = (size_t)row * N + col;
                if (EPI == 0) {
                    float* C = (float*)Cout;
                    C[off] = accumulate ? (C[off] + v) : v;
                } else if (EPI == 1) {
                    float s = v / (1.f + __expf(-v));
                    ((u16*)Cout)[off] = f2bf(s);
                } else {
                    ((float*)Cout)[off] = v + ext[off];
                }
            }
        }
}

// Per-token: sim = q . keys, per-(p,h) top-8, cartesian top-8 (JAX tie order),
// softmax gates, then 32-expert gather/dot/silu/accumulate -> expert states.
__global__ __launch_bounds__(256) void retrieve_expert(
    const float* __restrict__ Q, const float* __restrict__ keys,
    const float* __restrict__ hidden, const float* __restrict__ down_embed,
    const float* __restrict__ up_embed, float* __restrict__ expst) {
    __shared__ float qs[QDIM];
    __shared__ float sims[QDIM];
    __shared__ float topv[8][TOPK];
    __shared__ int topi[8][TOPK];
    __shared__ float sgate[NHEADS][TOPK];
    __shared__ int sidx[NHEADS][TOPK];
    __shared__ float red[NHEADS][HDIM];

    const int tok = blockIdx.x;
    const int tid = threadIdx.x;

    for (int i = tid; i < QDIM; i += 256) qs[i] = Q[(size_t)tok * QDIM + i];
    __syncthreads();

    for (int c = tid; c < QDIM; c += 256) {
        int p = c >> 8, rem = c & 255, h = rem >> 6, k = rem & 63;
        const float* kr = keys + (((h * NKEYS + k) * 2 + p) * 64);
        const float* qr = qs + p * 256 + h * 64;
        float s = 0.f;
#pragma unroll 8
        for (int n = 0; n < 64; n++) s += qr[n] * kr[n];
        sims[c] = s;  // group g = p*4+h at base g*64
    }
    __syncthreads();

    if (tid < 8) {  // per-(p,h) top-8, stable (lower index wins ties)
        const float* sv = sims + tid * 64;
        float bv[TOPK];
        int bi[TOPK];
#pragma unroll
        for (int i = 0; i < TOPK; i++) { bv[i] = -1e30f; bi[i] = 0; }
        for (int k = 0; k < 64; k++) {
            float v = sv[k];
            if (v > bv[TOPK - 1]) {
                int p2 = TOPK - 1;
                while (p2 > 0 && v > bv[p2 - 1]) {
                    bv[p2] = bv[p2 - 1]; bi[p2] = bi[p2 - 1]; p2--;
                }
                bv[p2] = v; bi[p2] = k;
            }
        }
#pragma unroll
        for (int i = 0; i < TOPK; i++) { topv[tid][i] = bv[i]; topi[tid][i] = bi[i]; }
    }
    __syncthreads();

    if (tid < NHEADS) {  // cartesian 8x8 -> top-8, pos order = i*8+j ascending
        int h = tid;
        float bv[TOPK];
        int bidx[TOPK];
#pragma unroll
        for (int i = 0; i < TOPK; i++) { bv[i] = -1e30f; bidx[i] = 0; }
        for (int i = 0; i < TOPK; i++)
            for (int j = 0; j < TOPK; j++) {
                float v = topv[h][i] + topv[4 + h][j];
                if (v > bv[TOPK - 1]) {
                    int p2 = TOPK - 1;
                    while (p2 > 0 && v > bv[p2 - 1]) {
                        bv[p2] = bv[p2 - 1]; bidx[p2] = bidx[p2 - 1]; p2--;
                    }
                    bv[p2] = v;
                    bidx[p2] = topi[h][i] * NKEYS + topi[4 + h][j];
                }
            }
        float m = bv[0], s = 0.f, e[TOPK];
#pragma unroll
        for (int i = 0; i < TOPK; i++) { e[i] = __expf(bv[i] - m); s += e[i]; }
        float inv = 1.f / s;
#pragma unroll
        for (int i = 0; i < TOPK; i++) { sgate[h][i] = e[i] * inv; sidx[h][i] = bidx[i]; }
    }
    __syncthreads();

    // expert phase: wave w = head w
    const int w = tid >> 6, l = tid & 63;
    float4 hid4[4], acc4[4];
    const float* hrow = hidden + (size_t)tok * HDIM;
#pragma unroll
    for (int j = 0; j < 4; j++) {
        hid4[j] = *reinterpret_cast<const float4*>(hrow + j * 256 + l * 4);
        acc4[j] = make_float4(0.f, 0.f, 0.f, 0.f);
    }
    for (int k = 0; k < TOPK; k++) {
        int e = sidx[w][k];
        const float* de = down_embed + (size_t)e * HDIM;
        float dot = 0.f;
#pragma unroll
        for (int j = 0; j < 4; j++) {
            float4 d4 = *reinterpret_cast<const float4*>(de + j * 256 + l * 4);
            dot += hid4[j].x * d4.x + hid4[j].y * d4.y + hid4[j].z * d4.z + hid4[j].w * d4.w;
        }
#pragma unroll
        for (int m = 32; m; m >>= 1) dot += __shfl_xor(dot, m, 64);
        float x = dot * sgate[w][k];
        float wk = x / (1.f + __expf(-x));
        const float* ue = up_embed + (size_t)e * HDIM;
#pragma unroll
        for (int j = 0; j < 4; j++) {
            float4 u4 = *reinterpret_cast<const float4*>(ue + j * 256 + l * 4);
            acc4[j].x += wk * u4.x; acc4[j].y += wk * u4.y;
            acc4[j].z += wk * u4.z; acc4[j].w += wk * u4.w;
        }
    }
#pragma unroll
    for (int j = 0; j < 4; j++)
        *reinterpret_cast<float4*>(&red[w][j * 256 + l * 4]) = acc4[j];
    __syncthreads();
    {
        int d = tid * 4;
        float4 s0 = *reinterpret_cast<float4*>(&red[0][d]);
        float4 s1 = *reinterpret_cast<float4*>(&red[1][d]);
        float4 s2 = *reinterpret_cast<float4*>(&red[2][d]);
        float4 s3 = *reinterpret_cast<float4*>(&red[3][d]);
        float4 s;
        s.x = s0.x + s1.x + s2.x + s3.x;
        s.y = s0.y + s1.y + s2.y + s3.y;
        s.z = s0.z + s1.z + s2.z + s3.z;
        s.w = s0.w + s1.w + s2.w + s3.w;
        *reinterpret_cast<float4*>(expst + (size_t)tok * HDIM + d) = s;
    }
}

extern "C" void kernel_launch(void* const* d_in, const int* in_sizes, int n_in,
                              void* d_out, int out_size, void* d_ws, size_t ws_size,
                              hipStream_t stream) {
    const float* hidden = (const float*)d_in[0];
    const float* W_up = (const float*)d_in[1];
    const float* W_down = (const float*)d_in[2];
    const float* W_q = (const float*)d_in[3];
    const float* keys = (const float*)d_in[4];
    const float* down_embed = (const float*)d_in[5];
    const float* up_embed = (const float*)d_in[6];
    float* out = (float*)d_out;

    char* ws = (char*)d_ws;
    size_t off = 0;
    auto alloc = [&](size_t bytes) {
        void* p = ws + off;
        off += (bytes + 255) & ~(size_t)255;
        return p;
    };
    u16* hid_hi = (u16*)alloc((size_t)TOKENS * HDIM * 2);
    u16* hid_lo = (u16*)alloc((size_t)TOKENS * HDIM * 2);
    u16* wq_hi = (u16*)alloc((size_t)QDIM * HDIM * 2);
    u16* wq_lo = (u16*)alloc((size_t)QDIM * HDIM * 2);
    u16* wup = (u16*)alloc((size_t)IDIM * HDIM * 2);
    u16* wdn = (u16*)alloc((size_t)HDIM * IDIM * 2);
    u16* act = (u16*)alloc((size_t)TOKENS * IDIM * 2);
    float* Qb = (float*)alloc((size_t)TOKENS * QDIM * 4);
    float* expst = (float*)alloc((size_t)TOKENS * HDIM * 4);

    cvt_kernel<<<(TOKENS * HDIM / 4 + 255) / 256, 256, 0, stream>>>(hidden, hid_hi, hid_lo,
                                                                    TOKENS * HDIM / 4);
    cvt_kernel<<<(QDIM * HDIM / 4 + 255) / 256, 256, 0, stream>>>(W_q, wq_hi, wq_lo,
                                                                  QDIM * HDIM / 4);
    cvt_kernel<<<(IDIM * HDIM / 4 + 255) / 256, 256, 0, stream>>>(W_up, wup, nullptr,
                                                                  IDIM * HDIM / 4);
    cvt_kernel<<<(HDIM * IDIM / 4 + 255) / 256, 256, 0, stream>>>(W_down, wdn, nullptr,
                                                                  HDIM * IDIM / 4);

    dim3 blk(256);
    // q projection, split-bf16: hi*hi + hi*lo + lo*hi
    gemm_bt<0><<<dim3(QDIM / BN, TOKENS / BM), blk, 0, stream>>>(hid_hi, wq_hi, Qb, nullptr,
                                                                 TOKENS, QDIM, HDIM, 0);
    gemm_bt<0><<<dim3(QDIM / BN, TOKENS / BM), blk, 0, stream>>>(hid_hi, wq_lo, Qb, nullptr,
                                                                 TOKENS, QDIM, HDIM, 1);
    gemm_bt<0><<<dim3(QDIM / BN, TOKENS / BM), blk, 0, stream>>>(hid_lo, wq_hi, Qb, nullptr,
                                                                 TOKENS, QDIM, HDIM, 1);

    retrieve_expert<<<TOKENS, 256, 0, stream>>>(Qb, keys, hidden, down_embed, up_embed,
                                                expst);

    gemm_bt<1><<<dim3(IDIM / BN, TOKENS / BM), blk, 0, stream>>>(hid_hi, wup, act, nullptr,
                                                                 TOKENS, IDIM, HDIM, 0);
    gemm_bt<2><<<dim3(HDIM / BN, TOKENS / BM), blk, 0, stream>>>(act, wdn, out, expst,
                                                                 TOKENS, HDIM, IDIM, 0);
}

// Round 2
// 513.197 us; speedup vs baseline: 1.0156x; 1.0156x over previous
//
#include <hip/hip_runtime.h>

typedef unsigned short u16;
typedef unsigned int u32;

#define TOKENS 4096   // B*T
#define HDIM 1024
#define IDIM 4096
#define NHEADS 4
#define NKEYS 64
#define TOPK 8
#define QDIM 512      // 2 * NHEADS * 64

typedef __bf16 bf16x8 __attribute__((ext_vector_type(8)));
typedef float  f32x4  __attribute__((ext_vector_type(4)));
typedef u16    u16x8  __attribute__((ext_vector_type(8)));
typedef u16    u16x4  __attribute__((ext_vector_type(4)));

__device__ __forceinline__ u16 f2bf(float f) {
    u32 u = __float_as_uint(f);
    u += 0x7fffu + ((u >> 16) & 1u);   // RNE
    return (u16)(u >> 16);
}
__device__ __forceinline__ float bf2f(u16 h) { return __uint_as_float(((u32)h) << 16); }

// fp32 -> bf16 hi (+ optional lo residual) conversion, vectorized
__global__ void cvt_kernel(const float* __restrict__ in, u16* __restrict__ hi,
                           u16* __restrict__ lo, int n4) {
    int i = blockIdx.x * blockDim.x + threadIdx.x;
    if (i >= n4) return;
    float4 v = reinterpret_cast<const float4*>(in)[i];
    float vf[4] = {v.x, v.y, v.z, v.w};
    ushort4 h;
    u16 hh[4];
#pragma unroll
    for (int j = 0; j < 4; j++) hh[j] = f2bf(vf[j]);
    h.x = hh[0]; h.y = hh[1]; h.z = hh[2]; h.w = hh[3];
    reinterpret_cast<ushort4*>(hi)[i] = h;
    if (lo) {
        ushort4 l4;
        u16 ll[4];
#pragma unroll
        for (int j = 0; j < 4; j++) ll[j] = f2bf(vf[j] - bf2f(hh[j]));
        l4.x = ll[0]; l4.y = ll[1]; l4.z = ll[2]; l4.w = ll[3];
        reinterpret_cast<ushort4*>(lo)[i] = l4;
    }
}

__device__ __forceinline__ void gload16(const void* g, void* s) {
    auto gp = reinterpret_cast<const __attribute__((address_space(1))) u32*>(
        reinterpret_cast<uintptr_t>(g));
    auto sp = reinterpret_cast<__attribute__((address_space(3))) u32*>(
        reinterpret_cast<uintptr_t>(s));
    __builtin_amdgcn_global_load_lds(gp, sp, 16, 0, 0);
}

#define BM 128
#define BN 128
#define BK 32

// C[M,N] = A[M,K] * B[N,K]^T   (bf16 in, fp32 accumulate)
// EPI 0: f32 store or += (accumulate flag)   (q projection)
// EPI 1: silu -> bf16 store                  (up proj)
// EPI 2: f32 store of acc + ext[row*N+col]   (down proj + expert states)
template <int EPI>
__global__ __launch_bounds__(256) void gemm_bt(const u16* __restrict__ A,
                                               const u16* __restrict__ B,
                                               void* __restrict__ Cout,
                                               const float* __restrict__ ext,
                                               int M, int N, int K, int accumulate) {
    __shared__ u16 As[BM * BK];
    __shared__ u16 Bs[BN * BK];
    const int t = threadIdx.x;
    const int lane = t & 63;
    const int wave = t >> 6;
    const int wr = wave >> 1, wc = wave & 1;
    const int m0 = blockIdx.y * BM;
    const int n0 = blockIdx.x * BN;

    f32x4 acc[4][4];
#pragma unroll
    for (int i = 0; i < 4; i++)
#pragma unroll
        for (int j = 0; j < 4; j++) acc[i][j] = (f32x4){0.f, 0.f, 0.f, 0.f};

    const size_t krow = (size_t)K * 2;  // bytes per row
    const int ro = lane & 15;
    const int ko = (lane >> 4) * 16;  // byte offset into 64B row

    for (int k0 = 0; k0 < K; k0 += BK) {
#pragma unroll
        for (int rnd = 0; rnd < 2; rnd++) {
            int o = t * 16 + rnd * 4096;
            int row = o >> 6, kb = o & 63;
            gload16((const char*)A + (size_t)(m0 + row) * krow + (size_t)k0 * 2 + kb,
                    (char*)As + o);
            gload16((const char*)B + (size_t)(n0 + row) * krow + (size_t)k0 * 2 + kb,
                    (char*)Bs + o);
        }
        __syncthreads();
        bf16x8 fa[4], fb[4];
#pragma unroll
        for (int i = 0; i < 4; i++) {
            fa[i] = *reinterpret_cast<const bf16x8*>((const char*)As +
                                                     (wr * 64 + i * 16 + ro) * 64 + ko);
            fb[i] = *reinterpret_cast<const bf16x8*>((const char*)Bs +
                                                     (wc * 64 + i * 16 + ro) * 64 + ko);
        }
#pragma unroll
        for (int i = 0; i < 4; i++)
#pragma unroll
            for (int j = 0; j < 4; j++)
                acc[i][j] = __builtin_amdgcn_mfma_f32_16x16x32_bf16(fa[i], fb[j],
                                                                    acc[i][j], 0, 0, 0);
        __syncthreads();
    }

#pragma unroll
    for (int i = 0; i < 4; i++)
#pragma unroll
        for (int j = 0; j < 4; j++) {
            int col = n0 + wc * 64 + j * 16 + (lane & 15);
            int rbase = m0 + wr * 64 + i * 16 + (lane >> 4) * 4;
#pragma unroll
            for (int r = 0; r < 4; r++) {
                int row = rbase + r;
                float v = acc[i][j][r];
                size_t off = (size_t)row * N + col;
                if (EPI == 0) {
                    float* C = (float*)Cout;
                    C[off] = accumulate ? (C[off] + v) : v;
                } else if (EPI == 1) {
                    float s = v / (1.f + __expf(-v));
                    ((u16*)Cout)[off] = f2bf(s);
                } else {
                    ((float*)Cout)[off] = v + ext[off];
                }
            }
        }
}

// Per-token: sim = q . keys, per-(p,h) top-8, cartesian top-8 (JAX tie order),
// softmax gates, then 32-expert bf16 gather/dot/silu/accumulate -> expert states.
// 512 threads: 8 waves. Dot phase: wave w -> head w>>1, experts (w&1)*4..+4
// (all loads issued up front, 4 independent reduce chains). Accumulate phase:
// wave w -> output quarter w>>1, expert half w&1 (16 pipelined 8B/lane loads).
__global__ __launch_bounds__(512) void router_expert(
    const float* __restrict__ Q, const float* __restrict__ keys,
    const float* __restrict__ hidden, const u16* __restrict__ de_bf,
    const u16* __restrict__ ue_bf, float* __restrict__ expst) {
    __shared__ float qs[QDIM];
    __shared__ float sims[QDIM];
    __shared__ float topv[8][TOPK];
    __shared__ int topi[8][TOPK];
    __shared__ float sgate[NHEADS][TOPK];
    __shared__ int sidx[NHEADS][TOPK];
    __shared__ float wkv[NHEADS][TOPK];
    __shared__ float red[8][256];

    const int tok = blockIdx.x;
    const int tid = threadIdx.x;

    qs[tid] = Q[(size_t)tok * QDIM + tid];
    __syncthreads();

    {   // one sim per thread: c = p*256 + h*64 + k
        int c = tid;
        int p = c >> 8, rem = c & 255, h = rem >> 6, k = rem & 63;
        const float4* kr =
            reinterpret_cast<const float4*>(keys + (((h * NKEYS + k) * 2 + p) * 64));
        const float4* qr = reinterpret_cast<const float4*>(qs + p * 256 + h * 64);
        float s = 0.f;
#pragma unroll
        for (int n = 0; n < 16; n++) {
            float4 a = qr[n], b = kr[n];
            s += a.x * b.x + a.y * b.y + a.z * b.z + a.w * b.w;
        }
        sims[c] = s;  // group g = p*4+h at base g*64
    }
    __syncthreads();

    if (tid < 8) {  // per-(p,h) top-8, stable (lower index wins ties)
        const float* sv = sims + tid * 64;
        float bv[TOPK];
        int bi[TOPK];
#pragma unroll
        for (int i = 0; i < TOPK; i++) { bv[i] = -1e30f; bi[i] = 0; }
        for (int k = 0; k < 64; k++) {
            float v = sv[k];
            if (v > bv[TOPK - 1]) {
                int p2 = TOPK - 1;
                while (p2 > 0 && v > bv[p2 - 1]) {
                    bv[p2] = bv[p2 - 1]; bi[p2] = bi[p2 - 1]; p2--;
                }
                bv[p2] = v; bi[p2] = k;
            }
        }
#pragma unroll
        for (int i = 0; i < TOPK; i++) { topv[tid][i] = bv[i]; topi[tid][i] = bi[i]; }
    }
    __syncthreads();

    if (tid < NHEADS) {  // cartesian 8x8 -> top-8, pos order = i*8+j ascending
        int h = tid;
        float bv[TOPK];
        int bidx[TOPK];
#pragma unroll
        for (int i = 0; i < TOPK; i++) { bv[i] = -1e30f; bidx[i] = 0; }
        for (int i = 0; i < TOPK; i++)
            for (int j = 0; j < TOPK; j++) {
                float v = topv[h][i] + topv[4 + h][j];
                if (v > bv[TOPK - 1]) {
                    int p2 = TOPK - 1;
                    while (p2 > 0 && v > bv[p2 - 1]) {
                        bv[p2] = bv[p2 - 1]; bidx[p2] = bidx[p2 - 1]; p2--;
                    }
                    bv[p2] = v;
                    bidx[p2] = topi[h][i] * NKEYS + topi[4 + h][j];
                }
            }
        float m = bv[0], s = 0.f, e[TOPK];
#pragma unroll
        for (int i = 0; i < TOPK; i++) { e[i] = __expf(bv[i] - m); s += e[i]; }
        float inv = 1.f / s;
#pragma unroll
        for (int i = 0; i < TOPK; i++) { sgate[h][i] = e[i] * inv; sidx[h][i] = bidx[i]; }
    }
    __syncthreads();

    const int w = tid >> 6, l = tid & 63;

    // ---- dot phase: wave w -> head w>>1, experts kq..kq+3 ----
    {
        const int head = w >> 1, kq = (w & 1) * 4;
        float h16[16];
        const float* hrow = hidden + (size_t)tok * HDIM + l * 16;
#pragma unroll
        for (int j = 0; j < 4; j++) {
            float4 v = reinterpret_cast<const float4*>(hrow)[j];
            h16[4 * j + 0] = v.x; h16[4 * j + 1] = v.y;
            h16[4 * j + 2] = v.z; h16[4 * j + 3] = v.w;
        }
        int eidx[4];
        float gt[4];
#pragma unroll
        for (int j = 0; j < 4; j++) {
            eidx[j] = sidx[head][kq + j];
            gt[j] = sgate[head][kq + j];
        }
        u16x8 dv[4][2];
#pragma unroll
        for (int j = 0; j < 4; j++) {
            const u16* dr = de_bf + (size_t)eidx[j] * HDIM + l * 16;
            dv[j][0] = *reinterpret_cast<const u16x8*>(dr);
            dv[j][1] = *reinterpret_cast<const u16x8*>(dr + 8);
        }
        float dot[4];
#pragma unroll
        for (int j = 0; j < 4; j++) {
            float s = 0.f;
#pragma unroll
            for (int t2 = 0; t2 < 8; t2++) s += h16[t2] * bf2f(dv[j][0][t2]);
#pragma unroll
            for (int t2 = 0; t2 < 8; t2++) s += h16[8 + t2] * bf2f(dv[j][1][t2]);
            dot[j] = s;
        }
#pragma unroll
        for (int m = 32; m; m >>= 1)
#pragma unroll
            for (int j = 0; j < 4; j++) dot[j] += __shfl_xor(dot[j], m, 64);
        if (l == 0) {
#pragma unroll
            for (int j = 0; j < 4; j++) {
                float x = dot[j] * gt[j];
                wkv[head][kq + j] = x / (1.f + __expf(-x));
            }
        }
    }
    __syncthreads();

    // ---- accumulate phase: wave w -> quarter q=w>>1, expert half hf=w&1 ----
    {
        const int q = w >> 1, hf = w & 1;
        float acc0 = 0.f, acc1 = 0.f, acc2 = 0.f, acc3 = 0.f;
        const u16* ubase = ue_bf + q * 256 + l * 4;
#pragma unroll
        for (int m = 0; m < 16; m++) {
            int mm = hf * 16 + m;
            int h = mm >> 3, k = mm & 7;
            int e = sidx[h][k];
            float wgt = wkv[h][k];
            u16x4 u = *reinterpret_cast<const u16x4*>(ubase + (size_t)e * HDIM);
            acc0 += wgt * bf2f(u[0]); acc1 += wgt * bf2f(u[1]);
            acc2 += wgt * bf2f(u[2]); acc3 += wgt * bf2f(u[3]);
        }
        float4 a4 = make_float4(acc0, acc1, acc2, acc3);
        *reinterpret_cast<float4*>(&red[w][l * 4]) = a4;
    }
    __syncthreads();

    {   // final: out[d] = red[2q][dq] + red[2q+1][dq], coalesced float2
        int d = tid * 2;
        int qq = d >> 8, dq = d & 255;
        float2 a = *reinterpret_cast<float2*>(&red[2 * qq][dq]);
        float2 b = *reinterpret_cast<float2*>(&red[2 * qq + 1][dq]);
        float2 o;
        o.x = a.x + b.x;
        o.y = a.y + b.y;
        *reinterpret_cast<float2*>(expst + (size_t)tok * HDIM + d) = o;
    }
}

extern "C" void kernel_launch(void* const* d_in, const int* in_sizes, int n_in,
                              void* d_out, int out_size, void* d_ws, size_t ws_size,
                              hipStream_t stream) {
    const float* hidden = (const float*)d_in[0];
    const float* W_up = (const float*)d_in[1];
    const float* W_down = (const float*)d_in[2];
    const float* W_q = (const float*)d_in[3];
    const float* keys = (const float*)d_in[4];
    const float* down_embed = (const float*)d_in[5];
    const float* up_embed = (const float*)d_in[6];
    float* out = (float*)d_out;

    char* ws = (char*)d_ws;
    size_t off = 0;
    auto alloc = [&](size_t bytes) {
        void* p = ws + off;
        off += (bytes + 255) & ~(size_t)255;
        return p;
    };
    u16* hid_hi = (u16*)alloc((size_t)TOKENS * HDIM * 2);
    u16* hid_lo = (u16*)alloc((size_t)TOKENS * HDIM * 2);
    u16* wq_hi = (u16*)alloc((size_t)QDIM * HDIM * 2);
    u16* wq_lo = (u16*)alloc((size_t)QDIM * HDIM * 2);
    u16* wup = (u16*)alloc((size_t)IDIM * HDIM * 2);
    u16* wdn = (u16*)alloc((size_t)HDIM * IDIM * 2);
    u16* act = (u16*)alloc((size_t)TOKENS * IDIM * 2);
    u16* de_bf = (u16*)alloc((size_t)4096 * HDIM * 2);
    u16* ue_bf = (u16*)alloc((size_t)4096 * HDIM * 2);
    float* Qb = (float*)alloc((size_t)TOKENS * QDIM * 4);
    float* expst = (float*)alloc((size_t)TOKENS * HDIM * 4);

    cvt_kernel<<<(TOKENS * HDIM / 4 + 255) / 256, 256, 0, stream>>>(hidden, hid_hi, hid_lo,
                                                                    TOKENS * HDIM / 4);
    cvt_kernel<<<(QDIM * HDIM / 4 + 255) / 256, 256, 0, stream>>>(W_q, wq_hi, wq_lo,
                                                                  QDIM * HDIM / 4);
    cvt_kernel<<<(IDIM * HDIM / 4 + 255) / 256, 256, 0, stream>>>(W_up, wup, nullptr,
                                                                  IDIM * HDIM / 4);
    cvt_kernel<<<(HDIM * IDIM / 4 + 255) / 256, 256, 0, stream>>>(W_down, wdn, nullptr,
                                                                  HDIM * IDIM / 4);
    cvt_kernel<<<(4096 * HDIM / 4 + 255) / 256, 256, 0, stream>>>(down_embed, de_bf,
                                                                  nullptr, 4096 * HDIM / 4);
    cvt_kernel<<<(4096 * HDIM / 4 + 255) / 256, 256, 0, stream>>>(up_embed, ue_bf,
                                                                  nullptr, 4096 * HDIM / 4);

    dim3 blk(256);
    // q projection, split-bf16: hi*hi + hi*lo + lo*hi
    gemm_bt<0><<<dim3(QDIM / BN, TOKENS / BM), blk, 0, stream>>>(hid_hi, wq_hi, Qb, nullptr,
                                                                 TOKENS, QDIM, HDIM, 0);
    gemm_bt<0><<<dim3(QDIM / BN, TOKENS / BM), blk, 0, stream>>>(hid_hi, wq_lo, Qb, nullptr,
                                                                 TOKENS, QDIM, HDIM, 1);
    gemm_bt<0><<<dim3(QDIM / BN, TOKENS / BM), blk, 0, stream>>>(hid_lo, wq_hi, Qb, nullptr,
                                                                 TOKENS, QDIM, HDIM, 1);

    router_expert<<<TOKENS, 512, 0, stream>>>(Qb, keys, hidden, de_bf, ue_bf, expst);

    gemm_bt<1><<<dim3(IDIM / BN, TOKENS / BM), blk, 0, stream>>>(hid_hi, wup, act, nullptr,
                                                                 TOKENS, IDIM, HDIM, 0);
    gemm_bt<2><<<dim3(HDIM / BN, TOKENS / BM), blk, 0, stream>>>(act, wdn, out, expst,
                                                                 TOKENS, HDIM, IDIM, 0);
}

// Round 3
// 424.690 us; speedup vs baseline: 1.2272x; 1.2084x over previous
//
#include <hip/hip_runtime.h>

typedef unsigned short u16;
typedef unsigned int u32;

#define TOKENS 4096   // B*T
#define HDIM 1024
#define IDIM 4096
#define NHEADS 4
#define NKEYS 64
#define TOPK 8
#define QDIM 512      // 2 * NHEADS * 64

typedef __bf16 bf16x8 __attribute__((ext_vector_type(8)));
typedef float  f32x4  __attribute__((ext_vector_type(4)));
typedef u16    u16x8  __attribute__((ext_vector_type(8)));
typedef u16    u16x4  __attribute__((ext_vector_type(4)));

__device__ __forceinline__ u16 f2bf(float f) {
    u32 u = __float_as_uint(f);
    u += 0x7fffu + ((u >> 16) & 1u);   // RNE
    return (u16)(u >> 16);
}
__device__ __forceinline__ float bf2f(u16 h) { return __uint_as_float(((u32)h) << 16); }

// fp32 -> bf16 hi (+ optional lo residual) conversion, vectorized
__global__ void cvt_kernel(const float* __restrict__ in, u16* __restrict__ hi,
                           u16* __restrict__ lo, int n4) {
    int i = blockIdx.x * blockDim.x + threadIdx.x;
    if (i >= n4) return;
    float4 v = reinterpret_cast<const float4*>(in)[i];
    float vf[4] = {v.x, v.y, v.z, v.w};
    ushort4 h;
    u16 hh[4];
#pragma unroll
    for (int j = 0; j < 4; j++) hh[j] = f2bf(vf[j]);
    h.x = hh[0]; h.y = hh[1]; h.z = hh[2]; h.w = hh[3];
    reinterpret_cast<ushort4*>(hi)[i] = h;
    if (lo) {
        ushort4 l4;
        u16 ll[4];
#pragma unroll
        for (int j = 0; j < 4; j++) ll[j] = f2bf(vf[j] - bf2f(hh[j]));
        l4.x = ll[0]; l4.y = ll[1]; l4.z = ll[2]; l4.w = ll[3];
        reinterpret_cast<ushort4*>(lo)[i] = l4;
    }
}

__device__ __forceinline__ void gload16(const void* g, void* s) {
    auto gp = reinterpret_cast<const __attribute__((address_space(1))) u32*>(
        reinterpret_cast<uintptr_t>(g));
    auto sp = reinterpret_cast<__attribute__((address_space(3))) u32*>(
        reinterpret_cast<uintptr_t>(s));
    __builtin_amdgcn_global_load_lds(gp, sp, 16, 0, 0);
}

#define BM 128
#define BN 128
#define BK 32

// C[M,N] = A[M,K] * B[N,K]^T   (bf16 in, fp32 accumulate)
// EPI 0: f32 store or += (accumulate flag)   (q projection)
// EPI 1: silu -> bf16 store                  (up proj)
// EPI 2: f32 store of acc + ext[row*N+col]   (down proj + expert states)
template <int EPI>
__global__ __launch_bounds__(256) void gemm_bt(const u16* __restrict__ A,
                                               const u16* __restrict__ B,
                                               void* __restrict__ Cout,
                                               const float* __restrict__ ext,
                                               int M, int N, int K, int accumulate) {
    __shared__ u16 As[BM * BK];
    __shared__ u16 Bs[BN * BK];
    const int t = threadIdx.x;
    const int lane = t & 63;
    const int wave = t >> 6;
    const int wr = wave >> 1, wc = wave & 1;
    const int m0 = blockIdx.y * BM;
    const int n0 = blockIdx.x * BN;

    f32x4 acc[4][4];
#pragma unroll
    for (int i = 0; i < 4; i++)
#pragma unroll
        for (int j = 0; j < 4; j++) acc[i][j] = (f32x4){0.f, 0.f, 0.f, 0.f};

    const size_t krow = (size_t)K * 2;  // bytes per row
    const int ro = lane & 15;
    const int ko = (lane >> 4) * 16;  // byte offset into 64B row

    for (int k0 = 0; k0 < K; k0 += BK) {
#pragma unroll
        for (int rnd = 0; rnd < 2; rnd++) {
            int o = t * 16 + rnd * 4096;
            int row = o >> 6, kb = o & 63;
            gload16((const char*)A + (size_t)(m0 + row) * krow + (size_t)k0 * 2 + kb,
                    (char*)As + o);
            gload16((const char*)B + (size_t)(n0 + row) * krow + (size_t)k0 * 2 + kb,
                    (char*)Bs + o);
        }
        __syncthreads();
        bf16x8 fa[4], fb[4];
#pragma unroll
        for (int i = 0; i < 4; i++) {
            fa[i] = *reinterpret_cast<const bf16x8*>((const char*)As +
                                                     (wr * 64 + i * 16 + ro) * 64 + ko);
            fb[i] = *reinterpret_cast<const bf16x8*>((const char*)Bs +
                                                     (wc * 64 + i * 16 + ro) * 64 + ko);
        }
#pragma unroll
        for (int i = 0; i < 4; i++)
#pragma unroll
            for (int j = 0; j < 4; j++)
                acc[i][j] = __builtin_amdgcn_mfma_f32_16x16x32_bf16(fa[i], fb[j],
                                                                    acc[i][j], 0, 0, 0);
        __syncthreads();
    }

#pragma unroll
    for (int i = 0; i < 4; i++)
#pragma unroll
        for (int j = 0; j < 4; j++) {
            int col = n0 + wc * 64 + j * 16 + (lane & 15);
            int rbase = m0 + wr * 64 + i * 16 + (lane >> 4) * 4;
#pragma unroll
            for (int r = 0; r < 4; r++) {
                int row = rbase + r;
                float v = acc[i][j][r];
                size_t off = (size_t)row * N + col;
                if (EPI == 0) {
                    float* C = (float*)Cout;
                    C[off] = accumulate ? (C[off] + v) : v;
                } else if (EPI == 1) {
                    float s = v / (1.f + __expf(-v));
                    ((u16*)Cout)[off] = f2bf(s);
                } else {
                    ((float*)Cout)[off] = v + ext[off];
                }
            }
        }
}

// Per-token router: sims, wave-parallel top-8 per (p,h) group, wave-parallel
// cartesian top-8 per head (JAX tie semantics: value desc, index/pos asc),
// softmax gates. Outputs sidx/gate [tok][4][8].
__global__ __launch_bounds__(512) void router(
    const float* __restrict__ Q, const float* __restrict__ keys,
    int* __restrict__ sidx_g, float* __restrict__ gate_g) {
    __shared__ float qs[QDIM];
    __shared__ float sims[QDIM];
    __shared__ float topv[8][TOPK];
    __shared__ int topi[8][TOPK];

    const int tok = blockIdx.x;
    const int tid = threadIdx.x;
    const int w = tid >> 6, l = tid & 63;

    qs[tid] = Q[(size_t)tok * QDIM + tid];
    __syncthreads();

    {   // one sim per thread: c = p*256 + h*64 + k
        int c = tid;
        int p = c >> 8, rem = c & 255, h = rem >> 6, k = rem & 63;
        const float4* kr =
            reinterpret_cast<const float4*>(keys + (((h * NKEYS + k) * 2 + p) * 64));
        const float4* qr = reinterpret_cast<const float4*>(qs + p * 256 + h * 64);
        float s = 0.f;
#pragma unroll
        for (int n = 0; n < 16; n++) {
            float4 a = qr[n], b = kr[n];
            s += a.x * b.x + a.y * b.y + a.z * b.z + a.w * b.w;
        }
        sims[c] = s;  // group g = p*4+h at base g*64
    }
    __syncthreads();

    {   // wave w handles group w: 8 rounds of 64-lane argmax (ties -> min idx)
        float v = sims[w * 64 + l];
        int idx = l;
        for (int r = 0; r < TOPK; r++) {
            float bv = v;
            int bi = idx;
#pragma unroll
            for (int m = 32; m; m >>= 1) {
                float ov = __shfl_xor(bv, m, 64);
                int oi = __shfl_xor(bi, m, 64);
                if (ov > bv || (ov == bv && oi < bi)) { bv = ov; bi = oi; }
            }
            if (l == 0) { topv[w][r] = bv; topi[w][r] = bi; }
            if (idx == bi) v = -3.4e38f;
        }
    }
    __syncthreads();

    if (w < NHEADS) {  // wave w = head w: 64 pair-sums, top-8 by (value, pos)
        const int h = w;
        const int i0 = l >> 3, j0 = l & 7;
        float vv = topv[h][i0] + topv[4 + h][j0];
        const int pos = l;
        float m0 = 0.f, myv = -3.4e38f;
        int myp = 0;
        for (int r = 0; r < TOPK; r++) {
            float bv = vv;
            int bp = pos;
#pragma unroll
            for (int m = 32; m; m >>= 1) {
                float ov = __shfl_xor(bv, m, 64);
                int op = __shfl_xor(bp, m, 64);
                if (ov > bv || (ov == bv && op < bp)) { bv = ov; bp = op; }
            }
            if (r == 0) m0 = bv;           // max (broadcast to all lanes)
            if (l == r) { myv = bv; myp = bp; }  // lane r owns rank r
            if (pos == bp) vv = -3.4e38f;
        }
        float e = __expf(myv - m0);        // lanes >= 8 have myv=-inf -> e=0
        float s = e;
#pragma unroll
        for (int m = 4; m; m >>= 1) s += __shfl_xor(s, m, 64);  // sum over lanes 0..7
        if (l < TOPK) {
            int bi = myp >> 3, bj = myp & 7;
            int eid = topi[h][bi] * NKEYS + topi[4 + h][bj];
            size_t o = ((size_t)tok * NHEADS + h) * TOPK + l;
            sidx_g[o] = eid;
            gate_g[o] = e / s;
        }
    }
}

// Streaming expert gather: one token per 256-thread block (4 waves).
// Dot phase: wave w -> experts 8w..8w+7, all 16x16B loads in flight.
// Acc phase: wave w -> output quarter w, 32 independent 8B/lane loads,
// direct global store (no cross-wave reduce).
__global__ __launch_bounds__(256) void expert_gather(
    const float* __restrict__ hidden, const u16* __restrict__ de_bf,
    const u16* __restrict__ ue_bf, const int* __restrict__ sidx_g,
    const float* __restrict__ gate_g, float* __restrict__ expst) {
    __shared__ float wks[32];
    __shared__ int eids_s[32];

    const int tok = blockIdx.x;
    const int w = threadIdx.x >> 6, l = threadIdx.x & 63;

    {   // dot phase
        float h16[16];
        const float* hrow = hidden + (size_t)tok * HDIM + l * 16;
#pragma unroll
        for (int j = 0; j < 4; j++) {
            float4 v = reinterpret_cast<const float4*>(hrow)[j];
            h16[4 * j + 0] = v.x; h16[4 * j + 1] = v.y;
            h16[4 * j + 2] = v.z; h16[4 * j + 3] = v.w;
        }
        int eid[8];
        float gt[8];
#pragma unroll
        for (int j = 0; j < 8; j++) {
            size_t o = (size_t)tok * 32 + w * 8 + j;
            eid[j] = sidx_g[o];
            gt[j] = gate_g[o];
        }
        u16x8 dv[8][2];
#pragma unroll
        for (int j = 0; j < 8; j++) {
            const u16* dr = de_bf + (size_t)eid[j] * HDIM + l * 16;
            dv[j][0] = *reinterpret_cast<const u16x8*>(dr);
            dv[j][1] = *reinterpret_cast<const u16x8*>(dr + 8);
        }
        float dot[8];
#pragma unroll
        for (int j = 0; j < 8; j++) {
            float s = 0.f;
#pragma unroll
            for (int t2 = 0; t2 < 8; t2++) s += h16[t2] * bf2f(dv[j][0][t2]);
#pragma unroll
            for (int t2 = 0; t2 < 8; t2++) s += h16[8 + t2] * bf2f(dv[j][1][t2]);
            dot[j] = s;
        }
#pragma unroll
        for (int m = 32; m; m >>= 1)
#pragma unroll
            for (int j = 0; j < 8; j++) dot[j] += __shfl_xor(dot[j], m, 64);
#pragma unroll
        for (int j = 0; j < 8; j++)
            if (l == j) {
                float x = dot[j] * gt[j];
                wks[w * 8 + j] = x / (1.f + __expf(-x));
                eids_s[w * 8 + j] = eid[j];
            }
    }
    __syncthreads();

    {   // acc phase: wave w owns dims [w*256, (w+1)*256)
        float acc0 = 0.f, acc1 = 0.f, acc2 = 0.f, acc3 = 0.f;
        const u16* ubase = ue_bf + w * 256 + l * 4;
#pragma unroll
        for (int m = 0; m < 32; m++) {
            int e = eids_s[m];
            float wk = wks[m];
            u16x4 u = *reinterpret_cast<const u16x4*>(ubase + (size_t)e * HDIM);
            acc0 += wk * bf2f(u[0]); acc1 += wk * bf2f(u[1]);
            acc2 += wk * bf2f(u[2]); acc3 += wk * bf2f(u[3]);
        }
        float4 a4 = make_float4(acc0, acc1, acc2, acc3);
        *reinterpret_cast<float4*>(expst + (size_t)tok * HDIM + w * 256 + l * 4) = a4;
    }
}

extern "C" void kernel_launch(void* const* d_in, const int* in_sizes, int n_in,
                              void* d_out, int out_size, void* d_ws, size_t ws_size,
                              hipStream_t stream) {
    const float* hidden = (const float*)d_in[0];
    const float* W_up = (const float*)d_in[1];
    const float* W_down = (const float*)d_in[2];
    const float* W_q = (const float*)d_in[3];
    const float* keys = (const float*)d_in[4];
    const float* down_embed = (const float*)d_in[5];
    const float* up_embed = (const float*)d_in[6];
    float* out = (float*)d_out;

    char* ws = (char*)d_ws;
    size_t off = 0;
    auto alloc = [&](size_t bytes) {
        void* p = ws + off;
        off += (bytes + 255) & ~(size_t)255;
        return p;
    };
    u16* hid_hi = (u16*)alloc((size_t)TOKENS * HDIM * 2);
    u16* hid_lo = (u16*)alloc((size_t)TOKENS * HDIM * 2);
    u16* wq_hi = (u16*)alloc((size_t)QDIM * HDIM * 2);
    u16* wq_lo = (u16*)alloc((size_t)QDIM * HDIM * 2);
    u16* wup = (u16*)alloc((size_t)IDIM * HDIM * 2);
    u16* wdn = (u16*)alloc((size_t)HDIM * IDIM * 2);
    u16* act = (u16*)alloc((size_t)TOKENS * IDIM * 2);
    u16* de_bf = (u16*)alloc((size_t)4096 * HDIM * 2);
    u16* ue_bf = (u16*)alloc((size_t)4096 * HDIM * 2);
    float* Qb = (float*)alloc((size_t)TOKENS * QDIM * 4);
    float* expst = (float*)alloc((size_t)TOKENS * HDIM * 4);
    int* sidx_g = (int*)alloc((size_t)TOKENS * 32 * 4);
    float* gate_g = (float*)alloc((size_t)TOKENS * 32 * 4);

    cvt_kernel<<<(TOKENS * HDIM / 4 + 255) / 256, 256, 0, stream>>>(hidden, hid_hi, hid_lo,
                                                                    TOKENS * HDIM / 4);
    cvt_kernel<<<(QDIM * HDIM / 4 + 255) / 256, 256, 0, stream>>>(W_q, wq_hi, wq_lo,
                                                                  QDIM * HDIM / 4);
    cvt_kernel<<<(IDIM * HDIM / 4 + 255) / 256, 256, 0, stream>>>(W_up, wup, nullptr,
                                                                  IDIM * HDIM / 4);
    cvt_kernel<<<(HDIM * IDIM / 4 + 255) / 256, 256, 0, stream>>>(W_down, wdn, nullptr,
                                                                  HDIM * IDIM / 4);
    cvt_kernel<<<(4096 * HDIM / 4 + 255) / 256, 256, 0, stream>>>(down_embed, de_bf,
                                                                  nullptr, 4096 * HDIM / 4);
    cvt_kernel<<<(4096 * HDIM / 4 + 255) / 256, 256, 0, stream>>>(up_embed, ue_bf,
                                                                  nullptr, 4096 * HDIM / 4);

    dim3 blk(256);
    // q projection, split-bf16: hi*hi + hi*lo + lo*hi
    gemm_bt<0><<<dim3(QDIM / BN, TOKENS / BM), blk, 0, stream>>>(hid_hi, wq_hi, Qb, nullptr,
                                                                 TOKENS, QDIM, HDIM, 0);
    gemm_bt<0><<<dim3(QDIM / BN, TOKENS / BM), blk, 0, stream>>>(hid_hi, wq_lo, Qb, nullptr,
                                                                 TOKENS, QDIM, HDIM, 1);
    gemm_bt<0><<<dim3(QDIM / BN, TOKENS / BM), blk, 0, stream>>>(hid_lo, wq_hi, Qb, nullptr,
                                                                 TOKENS, QDIM, HDIM, 1);

    router<<<TOKENS, 512, 0, stream>>>(Qb, keys, sidx_g, gate_g);
    expert_gather<<<TOKENS, 256, 0, stream>>>(hidden, de_bf, ue_bf, sidx_g, gate_g, expst);

    gemm_bt<1><<<dim3(IDIM / BN, TOKENS / BM), blk, 0, stream>>>(hid_hi, wup, act, nullptr,
                                                                 TOKENS, IDIM, HDIM, 0);
    gemm_bt<2><<<dim3(HDIM / BN, TOKENS / BM), blk, 0, stream>>>(act, wdn, out, expst,
                                                                 TOKENS, HDIM, IDIM, 0);
}

// Round 4
// 404.636 us; speedup vs baseline: 1.2880x; 1.0496x over previous
//
#include <hip/hip_runtime.h>

typedef unsigned short u16;
typedef unsigned int u32;

#define TOKENS 4096   // B*T
#define HDIM 1024
#define IDIM 4096
#define NHEADS 4
#define NKEYS 64
#define TOPK 8
#define QDIM 512      // 2 * NHEADS * 64

typedef __bf16 bf16x8 __attribute__((ext_vector_type(8)));
typedef float  f32x4  __attribute__((ext_vector_type(4)));
typedef u16    u16x8  __attribute__((ext_vector_type(8)));
typedef u16    u16x4  __attribute__((ext_vector_type(4)));

__device__ __forceinline__ u16 f2bf(float f) {
    u32 u = __float_as_uint(f);
    u += 0x7fffu + ((u >> 16) & 1u);   // RNE
    return (u16)(u >> 16);
}
__device__ __forceinline__ float bf2f(u16 h) { return __uint_as_float(((u32)h) << 16); }

// fp32 -> bf16 hi (+ optional lo residual) conversion, vectorized
__global__ void cvt_kernel(const float* __restrict__ in, u16* __restrict__ hi,
                           u16* __restrict__ lo, int n4) {
    int i = blockIdx.x * blockDim.x + threadIdx.x;
    if (i >= n4) return;
    float4 v = reinterpret_cast<const float4*>(in)[i];
    float vf[4] = {v.x, v.y, v.z, v.w};
    ushort4 h;
    u16 hh[4];
#pragma unroll
    for (int j = 0; j < 4; j++) hh[j] = f2bf(vf[j]);
    h.x = hh[0]; h.y = hh[1]; h.z = hh[2]; h.w = hh[3];
    reinterpret_cast<ushort4*>(hi)[i] = h;
    if (lo) {
        ushort4 l4;
        u16 ll[4];
#pragma unroll
        for (int j = 0; j < 4; j++) ll[j] = f2bf(vf[j] - bf2f(hh[j]));
        l4.x = ll[0]; l4.y = ll[1]; l4.z = ll[2]; l4.w = ll[3];
        reinterpret_cast<ushort4*>(lo)[i] = l4;
    }
}

__device__ __forceinline__ void gload16(const void* g, void* s) {
    auto gp = reinterpret_cast<const __attribute__((address_space(1))) u32*>(
        reinterpret_cast<uintptr_t>(g));
    auto sp = reinterpret_cast<__attribute__((address_space(3))) u32*>(
        reinterpret_cast<uintptr_t>(s));
    __builtin_amdgcn_global_load_lds(gp, sp, 16, 0, 0);
}

#define BM 128
#define BN 128
#define BK 32

// C[M,N] = A[M,K] * B[N,K]^T   (bf16 in, fp32 accumulate)
// EPI 0: f32 store or += (accumulate flag)   (q projection)
// EPI 1: silu -> bf16 store                  (up proj)
// EPI 2: f32 store of acc + ext[row*N+col]   (down proj + expert states)
template <int EPI>
__global__ __launch_bounds__(256) void gemm_bt(const u16* __restrict__ A,
                                               const u16* __restrict__ B,
                                               void* __restrict__ Cout,
                                               const float* __restrict__ ext,
                                               int M, int N, int K, int accumulate) {
    __shared__ u16 As[BM * BK];
    __shared__ u16 Bs[BN * BK];
    const int t = threadIdx.x;
    const int lane = t & 63;
    const int wave = t >> 6;
    const int wr = wave >> 1, wc = wave & 1;
    const int m0 = blockIdx.y * BM;
    const int n0 = blockIdx.x * BN;

    f32x4 acc[4][4];
#pragma unroll
    for (int i = 0; i < 4; i++)
#pragma unroll
        for (int j = 0; j < 4; j++) acc[i][j] = (f32x4){0.f, 0.f, 0.f, 0.f};

    const size_t krow = (size_t)K * 2;  // bytes per row
    const int ro = lane & 15;
    const int ko = (lane >> 4) * 16;  // byte offset into 64B row

    for (int k0 = 0; k0 < K; k0 += BK) {
#pragma unroll
        for (int rnd = 0; rnd < 2; rnd++) {
            int o = t * 16 + rnd * 4096;
            int row = o >> 6, kb = o & 63;
            gload16((const char*)A + (size_t)(m0 + row) * krow + (size_t)k0 * 2 + kb,
                    (char*)As + o);
            gload16((const char*)B + (size_t)(n0 + row) * krow + (size_t)k0 * 2 + kb,
                    (char*)Bs + o);
        }
        __syncthreads();
        bf16x8 fa[4], fb[4];
#pragma unroll
        for (int i = 0; i < 4; i++) {
            fa[i] = *reinterpret_cast<const bf16x8*>((const char*)As +
                                                     (wr * 64 + i * 16 + ro) * 64 + ko);
            fb[i] = *reinterpret_cast<const bf16x8*>((const char*)Bs +
                                                     (wc * 64 + i * 16 + ro) * 64 + ko);
        }
#pragma unroll
        for (int i = 0; i < 4; i++)
#pragma unroll
            for (int j = 0; j < 4; j++)
                acc[i][j] = __builtin_amdgcn_mfma_f32_16x16x32_bf16(fa[i], fb[j],
                                                                    acc[i][j], 0, 0, 0);
        __syncthreads();
    }

#pragma unroll
    for (int i = 0; i < 4; i++)
#pragma unroll
        for (int j = 0; j < 4; j++) {
            int col = n0 + wc * 64 + j * 16 + (lane & 15);
            int rbase = m0 + wr * 64 + i * 16 + (lane >> 4) * 4;
#pragma unroll
            for (int r = 0; r < 4; r++) {
                int row = rbase + r;
                float v = acc[i][j][r];
                size_t off = (size_t)row * N + col;
                if (EPI == 0) {
                    float* C = (float*)Cout;
                    C[off] = accumulate ? (C[off] + v) : v;
                } else if (EPI == 1) {
                    float s = v / (1.f + __expf(-v));
                    ((u16*)Cout)[off] = f2bf(s);
                } else {
                    ((float*)Cout)[off] = v + ext[off];
                }
            }
        }
}

// Rank of value v (lane l) among 64 values in LDS, JAX top_k tie order:
// rank = #{j: vj > v} + #{j < l: vj == v}. No cross-lane ops, 16 broadcast
// b128 reads, fully parallel.
__device__ __forceinline__ int rank64(const float* base, float v, int l) {
    const float4* gv = reinterpret_cast<const float4*>(base);
    int rank = 0;
#pragma unroll
    for (int n = 0; n < 16; n++) {
        float4 o = gv[n];
        int b = n * 4;
        rank += (o.x > v) || (o.x == v && (b + 0) < l);
        rank += (o.y > v) || (o.y == v && (b + 1) < l);
        rank += (o.z > v) || (o.z == v && (b + 2) < l);
        rank += (o.w > v) || (o.w == v && (b + 3) < l);
    }
    return rank;
}

// Per-token router: sims, rank-based top-8 per (p,h) group, rank-based
// cartesian top-8 per head (JAX tie semantics), softmax gates.
// Outputs sidx/gate [tok][4][8].
__global__ __launch_bounds__(512) void router(
    const float* __restrict__ Q, const float* __restrict__ keys,
    int* __restrict__ sidx_g, float* __restrict__ gate_g) {
    __shared__ float qs[QDIM];
    __shared__ float sims[QDIM];        // 8 groups x 64
    __shared__ float topv[8][TOPK];
    __shared__ int topi[8][TOPK];
    __shared__ float pv[NHEADS][64];    // cartesian pair-sums
    __shared__ float st8[NHEADS][TOPK];
    __shared__ int sid8[NHEADS][TOPK];

    const int tok = blockIdx.x;
    const int tid = threadIdx.x;
    const int w = tid >> 6, l = tid & 63;

    qs[tid] = Q[(size_t)tok * QDIM + tid];
    __syncthreads();

    {   // one sim per thread: c = p*256 + h*64 + k
        int c = tid;
        int p = c >> 8, rem = c & 255, h = rem >> 6, k = rem & 63;
        const float4* kr =
            reinterpret_cast<const float4*>(keys + (((h * NKEYS + k) * 2 + p) * 64));
        const float4* qr = reinterpret_cast<const float4*>(qs + p * 256 + h * 64);
        float s = 0.f;
#pragma unroll
        for (int n = 0; n < 16; n++) {
            float4 a = qr[n], b = kr[n];
            s += a.x * b.x + a.y * b.y + a.z * b.z + a.w * b.w;
        }
        sims[c] = s;  // group g = p*4+h at base g*64
    }
    __syncthreads();

    {   // phase A: wave w ranks its group's 64 sims
        float v = sims[w * 64 + l];
        int rank = rank64(sims + w * 64, v, l);
        if (rank < TOPK) { topv[w][rank] = v; topi[w][rank] = l; }
    }
    __syncthreads();

    if (w < NHEADS) {  // phase B: pair-sums (pos = i*8+j = l)
        pv[w][l] = topv[w][l >> 3] + topv[4 + w][l & 7];
    }
    __syncthreads();

    if (w < NHEADS) {  // rank 64 pair-sums, top-8 by (value desc, pos asc)
        float v = pv[w][l];
        int rank = rank64(pv[w], v, l);
        if (rank < TOPK) {
            st8[w][rank] = v;
            sid8[w][rank] = topi[w][l >> 3] * NKEYS + topi[4 + w][l & 7];
        }
    }
    __syncthreads();

    if (tid < NHEADS * TOPK) {  // softmax + output, one thread per (h, r)
        int h = tid >> 3, r = tid & 7;
        float m0 = st8[h][0];
        float s = 0.f;
#pragma unroll
        for (int i = 0; i < TOPK; i++) s += __expf(st8[h][i] - m0);
        size_t o = ((size_t)tok * NHEADS + h) * TOPK + r;
        sidx_g[o] = sid8[h][r];
        gate_g[o] = __expf(st8[h][r] - m0) / s;
    }
}

// Streaming expert gather: one token per 256-thread block (4 waves).
// Dot phase: wave w -> experts 8w..8w+7, all 16x16B loads in flight.
// Acc phase: wave w -> output quarter w, 32 independent 8B/lane loads,
// direct global store (no cross-wave reduce).
__global__ __launch_bounds__(256) void expert_gather(
    const float* __restrict__ hidden, const u16* __restrict__ de_bf,
    const u16* __restrict__ ue_bf, const int* __restrict__ sidx_g,
    const float* __restrict__ gate_g, float* __restrict__ expst) {
    __shared__ float wks[32];
    __shared__ int eids_s[32];

    const int tok = blockIdx.x;
    const int w = threadIdx.x >> 6, l = threadIdx.x & 63;

    {   // dot phase
        float h16[16];
        const float* hrow = hidden + (size_t)tok * HDIM + l * 16;
#pragma unroll
        for (int j = 0; j < 4; j++) {
            float4 v = reinterpret_cast<const float4*>(hrow)[j];
            h16[4 * j + 0] = v.x; h16[4 * j + 1] = v.y;
            h16[4 * j + 2] = v.z; h16[4 * j + 3] = v.w;
        }
        int eid[8];
        float gt[8];
#pragma unroll
        for (int j = 0; j < 8; j++) {
            size_t o = (size_t)tok * 32 + w * 8 + j;
            eid[j] = sidx_g[o];
            gt[j] = gate_g[o];
        }
        u16x8 dv[8][2];
#pragma unroll
        for (int j = 0; j < 8; j++) {
            const u16* dr = de_bf + (size_t)eid[j] * HDIM + l * 16;
            dv[j][0] = *reinterpret_cast<const u16x8*>(dr);
            dv[j][1] = *reinterpret_cast<const u16x8*>(dr + 8);
        }
        float dot[8];
#pragma unroll
        for (int j = 0; j < 8; j++) {
            float s = 0.f;
#pragma unroll
            for (int t2 = 0; t2 < 8; t2++) s += h16[t2] * bf2f(dv[j][0][t2]);
#pragma unroll
            for (int t2 = 0; t2 < 8; t2++) s += h16[8 + t2] * bf2f(dv[j][1][t2]);
            dot[j] = s;
        }
#pragma unroll
        for (int m = 32; m; m >>= 1)
#pragma unroll
            for (int j = 0; j < 8; j++) dot[j] += __shfl_xor(dot[j], m, 64);
#pragma unroll
        for (int j = 0; j < 8; j++)
            if (l == j) {
                float x = dot[j] * gt[j];
                wks[w * 8 + j] = x / (1.f + __expf(-x));
                eids_s[w * 8 + j] = eid[j];
            }
    }
    __syncthreads();

    {   // acc phase: wave w owns dims [w*256, (w+1)*256)
        float acc0 = 0.f, acc1 = 0.f, acc2 = 0.f, acc3 = 0.f;
        const u16* ubase = ue_bf + w * 256 + l * 4;
#pragma unroll
        for (int m = 0; m < 32; m++) {
            int e = eids_s[m];
            float wk = wks[m];
            u16x4 u = *reinterpret_cast<const u16x4*>(ubase + (size_t)e * HDIM);
            acc0 += wk * bf2f(u[0]); acc1 += wk * bf2f(u[1]);
            acc2 += wk * bf2f(u[2]); acc3 += wk * bf2f(u[3]);
        }
        float4 a4 = make_float4(acc0, acc1, acc2, acc3);
        *reinterpret_cast<float4*>(expst + (size_t)tok * HDIM + w * 256 + l * 4) = a4;
    }
}

extern "C" void kernel_launch(void* const* d_in, const int* in_sizes, int n_in,
                              void* d_out, int out_size, void* d_ws, size_t ws_size,
                              hipStream_t stream) {
    const float* hidden = (const float*)d_in[0];
    const float* W_up = (const float*)d_in[1];
    const float* W_down = (const float*)d_in[2];
    const float* W_q = (const float*)d_in[3];
    const float* keys = (const float*)d_in[4];
    const float* down_embed = (const float*)d_in[5];
    const float* up_embed = (const float*)d_in[6];
    float* out = (float*)d_out;

    char* ws = (char*)d_ws;
    size_t off = 0;
    auto alloc = [&](size_t bytes) {
        void* p = ws + off;
        off += (bytes + 255) & ~(size_t)255;
        return p;
    };
    u16* hid_hi = (u16*)alloc((size_t)TOKENS * HDIM * 2);
    u16* hid_lo = (u16*)alloc((size_t)TOKENS * HDIM * 2);
    u16* wq_hi = (u16*)alloc((size_t)QDIM * HDIM * 2);
    u16* wq_lo = (u16*)alloc((size_t)QDIM * HDIM * 2);
    u16* wup = (u16*)alloc((size_t)IDIM * HDIM * 2);
    u16* wdn = (u16*)alloc((size_t)HDIM * IDIM * 2);
    u16* act = (u16*)alloc((size_t)TOKENS * IDIM * 2);
    u16* de_bf = (u16*)alloc((size_t)4096 * HDIM * 2);
    u16* ue_bf = (u16*)alloc((size_t)4096 * HDIM * 2);
    float* Qb = (float*)alloc((size_t)TOKENS * QDIM * 4);
    float* expst = (float*)alloc((size_t)TOKENS * HDIM * 4);
    int* sidx_g = (int*)alloc((size_t)TOKENS * 32 * 4);
    float* gate_g = (float*)alloc((size_t)TOKENS * 32 * 4);

    cvt_kernel<<<(TOKENS * HDIM / 4 + 255) / 256, 256, 0, stream>>>(hidden, hid_hi, hid_lo,
                                                                    TOKENS * HDIM / 4);
    cvt_kernel<<<(QDIM * HDIM / 4 + 255) / 256, 256, 0, stream>>>(W_q, wq_hi, wq_lo,
                                                                  QDIM * HDIM / 4);
    cvt_kernel<<<(IDIM * HDIM / 4 + 255) / 256, 256, 0, stream>>>(W_up, wup, nullptr,
                                                                  IDIM * HDIM / 4);
    cvt_kernel<<<(HDIM * IDIM / 4 + 255) / 256, 256, 0, stream>>>(W_down, wdn, nullptr,
                                                                  HDIM * IDIM / 4);
    cvt_kernel<<<(4096 * HDIM / 4 + 255) / 256, 256, 0, stream>>>(down_embed, de_bf,
                                                                  nullptr, 4096 * HDIM / 4);
    cvt_kernel<<<(4096 * HDIM / 4 + 255) / 256, 256, 0, stream>>>(up_embed, ue_bf,
                                                                  nullptr, 4096 * HDIM / 4);

    dim3 blk(256);
    // q projection, split-bf16: hi*hi + hi*lo + lo*hi
    gemm_bt<0><<<dim3(QDIM / BN, TOKENS / BM), blk, 0, stream>>>(hid_hi, wq_hi, Qb, nullptr,
                                                                 TOKENS, QDIM, HDIM, 0);
    gemm_bt<0><<<dim3(QDIM / BN, TOKENS / BM), blk, 0, stream>>>(hid_hi, wq_lo, Qb, nullptr,
                                                                 TOKENS, QDIM, HDIM, 1);
    gemm_bt<0><<<dim3(QDIM / BN, TOKENS / BM), blk, 0, stream>>>(hid_lo, wq_hi, Qb, nullptr,
                                                                 TOKENS, QDIM, HDIM, 1);

    router<<<TOKENS, 512, 0, stream>>>(Qb, keys, sidx_g, gate_g);
    expert_gather<<<TOKENS, 256, 0, stream>>>(hidden, de_bf, ue_bf, sidx_g, gate_g, expst);

    gemm_bt<1><<<dim3(IDIM / BN, TOKENS / BM), blk, 0, stream>>>(hid_hi, wup, act, nullptr,
                                                                 TOKENS, IDIM, HDIM, 0);
    gemm_bt<2><<<dim3(HDIM / BN, TOKENS / BM), blk, 0, stream>>>(act, wdn, out, expst,
                                                                 TOKENS, HDIM, IDIM, 0);
}

// Round 5
// 311.669 us; speedup vs baseline: 1.6722x; 1.2983x over previous
//
#include <hip/hip_runtime.h>

typedef unsigned short u16;
typedef unsigned int u32;

#define TOKENS 4096   // B*T
#define HDIM 1024
#define IDIM 4096
#define NHEADS 4
#define NKEYS 64
#define TOPK 8
#define QDIM 512      // 2 * NHEADS * 64

typedef __bf16 bf16x8 __attribute__((ext_vector_type(8)));
typedef float  f32x4  __attribute__((ext_vector_type(4)));
typedef u16    u16x8  __attribute__((ext_vector_type(8)));
typedef u16    u16x4  __attribute__((ext_vector_type(4)));

__device__ __forceinline__ u16 f2bf(float f) {
    u32 u = __float_as_uint(f);
    u += 0x7fffu + ((u >> 16) & 1u);   // RNE
    return (u16)(u >> 16);
}
__device__ __forceinline__ float bf2f(u16 h) { return __uint_as_float(((u32)h) << 16); }

// ---- fused fp32->bf16 conversion over all tensors (one launch) ----
#define H_N4   1048576   // TOKENS*HDIM/4   (hi+lo)
#define Q_N4   131072    // QDIM*HDIM/4     (hi+lo)
#define WUP_N4 1048576
#define WDN_N4 1048576
#define DE_N4  1048576
#define UE_N4  1048576
#define CVT_TOT (H_N4 + Q_N4 + WUP_N4 + WDN_N4 + DE_N4 + UE_N4)

__device__ __forceinline__ void cvt1(const float* in, u16* hi, u16* lo, int i) {
    float4 v = reinterpret_cast<const float4*>(in)[i];
    float vf[4] = {v.x, v.y, v.z, v.w};
    ushort4 h;
    u16 hh[4];
#pragma unroll
    for (int j = 0; j < 4; j++) hh[j] = f2bf(vf[j]);
    h.x = hh[0]; h.y = hh[1]; h.z = hh[2]; h.w = hh[3];
    reinterpret_cast<ushort4*>(hi)[i] = h;
    if (lo) {
        ushort4 l4;
        u16 ll[4];
#pragma unroll
        for (int j = 0; j < 4; j++) ll[j] = f2bf(vf[j] - bf2f(hh[j]));
        l4.x = ll[0]; l4.y = ll[1]; l4.z = ll[2]; l4.w = ll[3];
        reinterpret_cast<ushort4*>(lo)[i] = l4;
    }
}

__global__ __launch_bounds__(256) void cvt_all(
    const float* __restrict__ hidden, const float* __restrict__ W_q,
    const float* __restrict__ W_up, const float* __restrict__ W_down,
    const float* __restrict__ de, const float* __restrict__ ue,
    u16* __restrict__ hid_hi, u16* __restrict__ hid_lo,
    u16* __restrict__ wq_hi, u16* __restrict__ wq_lo,
    u16* __restrict__ wup, u16* __restrict__ wdn,
    u16* __restrict__ de_bf, u16* __restrict__ ue_bf) {
    int i = blockIdx.x * 256 + threadIdx.x;
    if (i >= CVT_TOT) return;
    if (i < H_N4) { cvt1(hidden, hid_hi, hid_lo, i); return; }
    i -= H_N4;
    if (i < Q_N4) { cvt1(W_q, wq_hi, wq_lo, i); return; }
    i -= Q_N4;
    if (i < WUP_N4) { cvt1(W_up, wup, nullptr, i); return; }
    i -= WUP_N4;
    if (i < WDN_N4) { cvt1(W_down, wdn, nullptr, i); return; }
    i -= WDN_N4;
    if (i < DE_N4) { cvt1(de, de_bf, nullptr, i); return; }
    i -= DE_N4;
    cvt1(ue, ue_bf, nullptr, i);
}

__device__ __forceinline__ void gload16(const void* g, void* s) {
    auto gp = reinterpret_cast<const __attribute__((address_space(1))) u32*>(
        reinterpret_cast<uintptr_t>(g));
    auto sp = reinterpret_cast<__attribute__((address_space(3))) u32*>(
        reinterpret_cast<uintptr_t>(s));
    __builtin_amdgcn_global_load_lds(gp, sp, 16, 0, 0);
}

#define BK 32

// LDS tile layout: rows of 64B (32 bf16). Swizzle: 16B slot ^= (row>>1)&3,
// i.e. addr ^= ((addr>>7)&3)<<4. Applied on global SOURCE at staging (LDS
// dest stays linear, per global_load_lds constraint) and on fragment reads.
// Bank effect: the 64 lanes' ds_read_b128 cover all 64 slots of 16 rows
// bijectively -> 2 lanes/bank = conflict-free (was 8-way).
__device__ __forceinline__ int swz(int a) { return a ^ (((a >> 7) & 3) << 4); }

template <int ROWS>
__device__ __forceinline__ void stage_tile(const u16* g, size_t krow_b, size_t kb0,
                                           u16* s, int t) {
#pragma unroll
    for (int rnd = 0; rnd < ROWS / 64; rnd++) {
        int o = t * 16 + rnd * 4096;
        int os = swz(o);
        int row = o >> 6, kb = os & 63;
        gload16((const char*)g + (size_t)row * krow_b + kb0 + kb, (char*)s + o);
    }
}

// C[M,N] = A[M,K]*B[N,K]^T (+ SPLIT: A_lo*B + A*B_lo), bf16 in, fp32 acc.
// EPI 0: f32 store                           (q projection, fused split)
// EPI 1: silu -> bf16 store                  (up proj)
// EPI 2: f32 store of acc + ext[row*N+col]   (down proj + expert states)
template <int EPI, int TBM, int TBN, bool SPLIT>
__global__ __launch_bounds__(256) void gemm_bt(
    const u16* __restrict__ A, const u16* __restrict__ Alo,
    const u16* __restrict__ B, const u16* __restrict__ Blo,
    void* __restrict__ Cout, const float* __restrict__ ext,
    int M, int N, int K) {
    constexpr int NS = SPLIT ? 2 : 1;
    constexpr int WM = TBM / 2, WN = TBN / 2;
    constexpr int FM = WM / 16, FN = WN / 16;
    __shared__ u16 As[NS * TBM * BK];
    __shared__ u16 Bs[NS * TBN * BK];
    const int t = threadIdx.x;
    const int lane = t & 63;
    const int wave = t >> 6;
    const int wr = wave >> 1, wc = wave & 1;
    const int m0 = blockIdx.y * TBM;
    const int n0 = blockIdx.x * TBN;

    f32x4 acc[FM][FN];
#pragma unroll
    for (int i = 0; i < FM; i++)
#pragma unroll
        for (int j = 0; j < FN; j++) acc[i][j] = (f32x4){0.f, 0.f, 0.f, 0.f};

    const size_t krow = (size_t)K * 2;  // bytes per row
    const int ro = lane & 15;
    const int ko = (lane >> 4) * 16;  // byte offset into 64B row

    const u16* Ab = A + (size_t)m0 * K;
    const u16* Bb = B + (size_t)n0 * K;
    const u16* Alb = SPLIT ? Alo + (size_t)m0 * K : nullptr;
    const u16* Blb = SPLIT ? Blo + (size_t)n0 * K : nullptr;

    for (int k0 = 0; k0 < K; k0 += BK) {
        size_t kb0 = (size_t)k0 * 2;
        stage_tile<TBM>(Ab, krow, kb0, As, t);
        stage_tile<TBN>(Bb, krow, kb0, Bs, t);
        if (SPLIT) {
            stage_tile<TBM>(Alb, krow, kb0, As + TBM * BK, t);
            stage_tile<TBN>(Blb, krow, kb0, Bs + TBN * BK, t);
        }
        __syncthreads();
        bf16x8 fa[FM], fb[FN], fal[FM], fbl[FN];
#pragma unroll
        for (int i = 0; i < FM; i++) {
            int a = swz((wr * WM + i * 16 + ro) * 64 + ko);
            fa[i] = *reinterpret_cast<const bf16x8*>((const char*)As + a);
            if (SPLIT)
                fal[i] = *reinterpret_cast<const bf16x8*>((const char*)(As + TBM * BK) + a);
        }
#pragma unroll
        for (int j = 0; j < FN; j++) {
            int a = swz((wc * WN + j * 16 + ro) * 64 + ko);
            fb[j] = *reinterpret_cast<const bf16x8*>((const char*)Bs + a);
            if (SPLIT)
                fbl[j] = *reinterpret_cast<const bf16x8*>((const char*)(Bs + TBN * BK) + a);
        }
#pragma unroll
        for (int i = 0; i < FM; i++)
#pragma unroll
            for (int j = 0; j < FN; j++) {
                acc[i][j] = __builtin_amdgcn_mfma_f32_16x16x32_bf16(fa[i], fb[j],
                                                                    acc[i][j], 0, 0, 0);
                if (SPLIT) {
                    acc[i][j] = __builtin_amdgcn_mfma_f32_16x16x32_bf16(fa[i], fbl[j],
                                                                        acc[i][j], 0, 0, 0);
                    acc[i][j] = __builtin_amdgcn_mfma_f32_16x16x32_bf16(fal[i], fb[j],
                                                                        acc[i][j], 0, 0, 0);
                }
            }
        __syncthreads();
    }

#pragma unroll
    for (int i = 0; i < FM; i++)
#pragma unroll
        for (int j = 0; j < FN; j++) {
            int col = n0 + wc * WN + j * 16 + (lane & 15);
            int rbase = m0 + wr * WM + i * 16 + (lane >> 4) * 4;
#pragma unroll
            for (int r = 0; r < 4; r++) {
                int row = rbase + r;
                float v = acc[i][j][r];
                size_t off = (size_t)row * N + col;
                if (EPI == 0) {
                    ((float*)Cout)[off] = v;
                } else if (EPI == 1) {
                    float s = v / (1.f + __expf(-v));
                    ((u16*)Cout)[off] = f2bf(s);
                } else {
                    ((float*)Cout)[off] = v + ext[off];
                }
            }
        }
}

// Rank of value v (lane l) among 64 values in LDS, JAX top_k tie order:
// rank = #{j: vj > v} + #{j < l: vj == v}. No cross-lane ops, 16 broadcast
// b128 reads, fully parallel.
__device__ __forceinline__ int rank64(const float* base, float v, int l) {
    const float4* gv = reinterpret_cast<const float4*>(base);
    int rank = 0;
#pragma unroll
    for (int n = 0; n < 16; n++) {
        float4 o = gv[n];
        int b = n * 4;
        rank += (o.x > v) || (o.x == v && (b + 0) < l);
        rank += (o.y > v) || (o.y == v && (b + 1) < l);
        rank += (o.z > v) || (o.z == v && (b + 2) < l);
        rank += (o.w > v) || (o.w == v && (b + 3) < l);
    }
    return rank;
}

// Per-token router: sims, rank-based top-8 per (p,h) group, rank-based
// cartesian top-8 per head (JAX tie semantics), softmax gates.
// Outputs sidx/gate [tok][4][8].
__global__ __launch_bounds__(512) void router(
    const float* __restrict__ Q, const float* __restrict__ keys,
    int* __restrict__ sidx_g, float* __restrict__ gate_g) {
    __shared__ float qs[QDIM];
    __shared__ float sims[QDIM];        // 8 groups x 64
    __shared__ float topv[8][TOPK];
    __shared__ int topi[8][TOPK];
    __shared__ float pv[NHEADS][64];    // cartesian pair-sums
    __shared__ float st8[NHEADS][TOPK];
    __shared__ int sid8[NHEADS][TOPK];

    const int tok = blockIdx.x;
    const int tid = threadIdx.x;
    const int w = tid >> 6, l = tid & 63;

    qs[tid] = Q[(size_t)tok * QDIM + tid];
    __syncthreads();

    {   // one sim per thread: c = p*256 + h*64 + k
        int c = tid;
        int p = c >> 8, rem = c & 255, h = rem >> 6, k = rem & 63;
        const float4* kr =
            reinterpret_cast<const float4*>(keys + (((h * NKEYS + k) * 2 + p) * 64));
        const float4* qr = reinterpret_cast<const float4*>(qs + p * 256 + h * 64);
        float s = 0.f;
#pragma unroll
        for (int n = 0; n < 16; n++) {
            float4 a = qr[n], b = kr[n];
            s += a.x * b.x + a.y * b.y + a.z * b.z + a.w * b.w;
        }
        sims[c] = s;  // group g = p*4+h at base g*64
    }
    __syncthreads();

    {   // phase A: wave w ranks its group's 64 sims
        float v = sims[w * 64 + l];
        int rank = rank64(sims + w * 64, v, l);
        if (rank < TOPK) { topv[w][rank] = v; topi[w][rank] = l; }
    }
    __syncthreads();

    if (w < NHEADS) {  // phase B: pair-sums (pos = i*8+j = l)
        pv[w][l] = topv[w][l >> 3] + topv[4 + w][l & 7];
    }
    __syncthreads();

    if (w < NHEADS) {  // rank 64 pair-sums, top-8 by (value desc, pos asc)
        float v = pv[w][l];
        int rank = rank64(pv[w], v, l);
        if (rank < TOPK) {
            st8[w][rank] = v;
            sid8[w][rank] = topi[w][l >> 3] * NKEYS + topi[4 + w][l & 7];
        }
    }
    __syncthreads();

    if (tid < NHEADS * TOPK) {  // softmax + output, one thread per (h, r)
        int h = tid >> 3, r = tid & 7;
        float m0 = st8[h][0];
        float s = 0.f;
#pragma unroll
        for (int i = 0; i < TOPK; i++) s += __expf(st8[h][i] - m0);
        size_t o = ((size_t)tok * NHEADS + h) * TOPK + r;
        sidx_g[o] = sid8[h][r];
        gate_g[o] = __expf(st8[h][r] - m0) / s;
    }
}

// Streaming expert gather: one token per 256-thread block (4 waves).
// Dot phase (bf16 hidden): wave w -> experts 8w..8w+7, all loads in flight.
// Acc phase: wave w -> output quarter w, 32 independent 8B/lane loads,
// direct global store (no cross-wave reduce).
__global__ __launch_bounds__(256) void expert_gather(
    const u16* __restrict__ hid_bf, const u16* __restrict__ de_bf,
    const u16* __restrict__ ue_bf, const int* __restrict__ sidx_g,
    const float* __restrict__ gate_g, float* __restrict__ expst) {
    __shared__ float wks[32];
    __shared__ int eids_s[32];

    const int tok = blockIdx.x;
    const int w = threadIdx.x >> 6, l = threadIdx.x & 63;

    {   // dot phase
        u16x8 hv[2];
        const u16* hrow = hid_bf + (size_t)tok * HDIM + l * 16;
        hv[0] = *reinterpret_cast<const u16x8*>(hrow);
        hv[1] = *reinterpret_cast<const u16x8*>(hrow + 8);
        float h16[16];
#pragma unroll
        for (int t2 = 0; t2 < 8; t2++) { h16[t2] = bf2f(hv[0][t2]); h16[8 + t2] = bf2f(hv[1][t2]); }
        int eid[8];
        float gt[8];
#pragma unroll
        for (int j = 0; j < 8; j++) {
            size_t o = (size_t)tok * 32 + w * 8 + j;
            eid[j] = sidx_g[o];
            gt[j] = gate_g[o];
        }
        u16x8 dv[8][2];
#pragma unroll
        for (int j = 0; j < 8; j++) {
            const u16* dr = de_bf + (size_t)eid[j] * HDIM + l * 16;
            dv[j][0] = *reinterpret_cast<const u16x8*>(dr);
            dv[j][1] = *reinterpret_cast<const u16x8*>(dr + 8);
        }
        float dot[8];
#pragma unroll
        for (int j = 0; j < 8; j++) {
            float s = 0.f;
#pragma unroll
            for (int t2 = 0; t2 < 8; t2++) s += h16[t2] * bf2f(dv[j][0][t2]);
#pragma unroll
            for (int t2 = 0; t2 < 8; t2++) s += h16[8 + t2] * bf2f(dv[j][1][t2]);
            dot[j] = s;
        }
#pragma unroll
        for (int m = 32; m; m >>= 1)
#pragma unroll
            for (int j = 0; j < 8; j++) dot[j] += __shfl_xor(dot[j], m, 64);
#pragma unroll
        for (int j = 0; j < 8; j++)
            if (l == j) {
                float x = dot[j] * gt[j];
                wks[w * 8 + j] = x / (1.f + __expf(-x));
                eids_s[w * 8 + j] = eid[j];
            }
    }
    __syncthreads();

    {   // acc phase: wave w owns dims [w*256, (w+1)*256)
        float acc0 = 0.f, acc1 = 0.f, acc2 = 0.f, acc3 = 0.f;
        const u16* ubase = ue_bf + w * 256 + l * 4;
#pragma unroll
        for (int m = 0; m < 32; m++) {
            int e = eids_s[m];
            float wk = wks[m];
            u16x4 u = *reinterpret_cast<const u16x4*>(ubase + (size_t)e * HDIM);
            acc0 += wk * bf2f(u[0]); acc1 += wk * bf2f(u[1]);
            acc2 += wk * bf2f(u[2]); acc3 += wk * bf2f(u[3]);
        }
        float4 a4 = make_float4(acc0, acc1, acc2, acc3);
        *reinterpret_cast<float4*>(expst + (size_t)tok * HDIM + w * 256 + l * 4) = a4;
    }
}

extern "C" void kernel_launch(void* const* d_in, const int* in_sizes, int n_in,
                              void* d_out, int out_size, void* d_ws, size_t ws_size,
                              hipStream_t stream) {
    const float* hidden = (const float*)d_in[0];
    const float* W_up = (const float*)d_in[1];
    const float* W_down = (const float*)d_in[2];
    const float* W_q = (const float*)d_in[3];
    const float* keys = (const float*)d_in[4];
    const float* down_embed = (const float*)d_in[5];
    const float* up_embed = (const float*)d_in[6];
    float* out = (float*)d_out;

    char* ws = (char*)d_ws;
    size_t off = 0;
    auto alloc = [&](size_t bytes) {
        void* p = ws + off;
        off += (bytes + 255) & ~(size_t)255;
        return p;
    };
    u16* hid_hi = (u16*)alloc((size_t)TOKENS * HDIM * 2);
    u16* hid_lo = (u16*)alloc((size_t)TOKENS * HDIM * 2);
    u16* wq_hi = (u16*)alloc((size_t)QDIM * HDIM * 2);
    u16* wq_lo = (u16*)alloc((size_t)QDIM * HDIM * 2);
    u16* wup = (u16*)alloc((size_t)IDIM * HDIM * 2);
    u16* wdn = (u16*)alloc((size_t)HDIM * IDIM * 2);
    u16* act = (u16*)alloc((size_t)TOKENS * IDIM * 2);
    u16* de_bf = (u16*)alloc((size_t)4096 * HDIM * 2);
    u16* ue_bf = (u16*)alloc((size_t)4096 * HDIM * 2);
    float* Qb = (float*)alloc((size_t)TOKENS * QDIM * 4);
    float* expst = (float*)alloc((size_t)TOKENS * HDIM * 4);
    int* sidx_g = (int*)alloc((size_t)TOKENS * 32 * 4);
    float* gate_g = (float*)alloc((size_t)TOKENS * 32 * 4);

    cvt_all<<<(CVT_TOT + 255) / 256, 256, 0, stream>>>(
        hidden, W_q, W_up, W_down, down_embed, up_embed,
        hid_hi, hid_lo, wq_hi, wq_lo, wup, wdn, de_bf, ue_bf);

    dim3 blk(256);
    // q projection, fused split-bf16: hi*hi + hi*lo + lo*hi, 64x128 tile
    gemm_bt<0, 64, 128, true><<<dim3(QDIM / 128, TOKENS / 64), blk, 0, stream>>>(
        hid_hi, hid_lo, wq_hi, wq_lo, Qb, nullptr, TOKENS, QDIM, HDIM);

    router<<<TOKENS, 512, 0, stream>>>(Qb, keys, sidx_g, gate_g);
    expert_gather<<<TOKENS, 256, 0, stream>>>(hid_hi, de_bf, ue_bf, sidx_g, gate_g, expst);

    // up proj: 128x128 tile, grid 1024
    gemm_bt<1, 128, 128, false><<<dim3(IDIM / 128, TOKENS / 128), blk, 0, stream>>>(
        hid_hi, nullptr, wup, nullptr, act, nullptr, TOKENS, IDIM, HDIM);
    // down proj: 128x64 tile, grid 512 (2 blocks/CU)
    gemm_bt<2, 128, 64, false><<<dim3(HDIM / 64, TOKENS / 128), blk, 0, stream>>>(
        act, nullptr, wdn, nullptr, out, expst, TOKENS, HDIM, IDIM);
}

// Round 6
// 278.315 us; speedup vs baseline: 1.8726x; 1.1198x over previous
//
#include <hip/hip_runtime.h>

typedef unsigned short u16;
typedef unsigned int u32;

#define TOKENS 4096   // B*T
#define HDIM 1024
#define IDIM 4096
#define NHEADS 4
#define NKEYS 64
#define TOPK 8
#define QDIM 512      // 2 * NHEADS * 64

typedef __bf16 bf16x8 __attribute__((ext_vector_type(8)));
typedef float  f32x4  __attribute__((ext_vector_type(4)));
typedef u16    u16x8  __attribute__((ext_vector_type(8)));
typedef u16    u16x4  __attribute__((ext_vector_type(4)));
typedef u32    u32x4  __attribute__((ext_vector_type(4)));

__device__ __forceinline__ u16 f2bf(float f) {
    u32 u = __float_as_uint(f);
    u += 0x7fffu + ((u >> 16) & 1u);   // RNE
    return (u16)(u >> 16);
}
__device__ __forceinline__ float bf2f(u16 h) { return __uint_as_float(((u32)h) << 16); }

// ---- fused fp32->bf16 / fp32->fp8 conversion over all tensors ----
#define H_N4   1048576   // TOKENS*HDIM/4   (hi+lo)
#define Q_N4   131072    // QDIM*HDIM/4     (hi+lo)
#define WUP_N4 1048576
#define WDN_N4 1048576
#define DE_N4  1048576
#define UE_N4  1048576
#define CVT_TOT (H_N4 + Q_N4 + WUP_N4 + WDN_N4 + DE_N4 + UE_N4)

__device__ __forceinline__ void cvt1(const float* in, u16* hi, u16* lo, int i) {
    float4 v = reinterpret_cast<const float4*>(in)[i];
    float vf[4] = {v.x, v.y, v.z, v.w};
    ushort4 h;
    u16 hh[4];
#pragma unroll
    for (int j = 0; j < 4; j++) hh[j] = f2bf(vf[j]);
    h.x = hh[0]; h.y = hh[1]; h.z = hh[2]; h.w = hh[3];
    reinterpret_cast<ushort4*>(hi)[i] = h;
    if (lo) {
        ushort4 l4;
        u16 ll[4];
#pragma unroll
        for (int j = 0; j < 4; j++) ll[j] = f2bf(vf[j] - bf2f(hh[j]));
        l4.x = ll[0]; l4.y = ll[1]; l4.z = ll[2]; l4.w = ll[3];
        reinterpret_cast<ushort4*>(lo)[i] = l4;
    }
}

__device__ __forceinline__ void cvt1_f8(const float* in, u32* out8, int i) {
    float4 v = reinterpret_cast<const float4*>(in)[i];
    u32 w = __builtin_amdgcn_cvt_pk_fp8_f32(v.x, v.y, 0u, false);
    w = __builtin_amdgcn_cvt_pk_fp8_f32(v.z, v.w, w, true);
    out8[i] = w;
}

__global__ __launch_bounds__(256) void cvt_all(
    const float* __restrict__ hidden, const float* __restrict__ W_q,
    const float* __restrict__ W_up, const float* __restrict__ W_down,
    const float* __restrict__ de, const float* __restrict__ ue,
    u16* __restrict__ hid_hi, u16* __restrict__ hid_lo,
    u16* __restrict__ wq_hi, u16* __restrict__ wq_lo,
    u16* __restrict__ wup, u16* __restrict__ wdn,
    u32* __restrict__ de_f8, u32* __restrict__ ue_f8) {
    int i = blockIdx.x * 256 + threadIdx.x;
    if (i >= CVT_TOT) return;
    if (i < H_N4) { cvt1(hidden, hid_hi, hid_lo, i); return; }
    i -= H_N4;
    if (i < Q_N4) { cvt1(W_q, wq_hi, wq_lo, i); return; }
    i -= Q_N4;
    if (i < WUP_N4) { cvt1(W_up, wup, nullptr, i); return; }
    i -= WUP_N4;
    if (i < WDN_N4) { cvt1(W_down, wdn, nullptr, i); return; }
    i -= WDN_N4;
    if (i < DE_N4) { cvt1_f8(de, de_f8, i); return; }
    i -= DE_N4;
    cvt1_f8(ue, ue_f8, i);
}

// out += partial (after both K-chunks of down proj completed)
__global__ __launch_bounds__(256) void reduce_add(float* __restrict__ out,
                                                  const float* __restrict__ p, int n4) {
    int i = blockIdx.x * 256 + threadIdx.x;
    if (i >= n4) return;
    float4 a = reinterpret_cast<const float4*>(out)[i];
    float4 b = reinterpret_cast<const float4*>(p)[i];
    a.x += b.x; a.y += b.y; a.z += b.z; a.w += b.w;
    reinterpret_cast<float4*>(out)[i] = a;
}

__device__ __forceinline__ void gload16(const void* g, void* s) {
    auto gp = reinterpret_cast<const __attribute__((address_space(1))) u32*>(
        reinterpret_cast<uintptr_t>(g));
    auto sp = reinterpret_cast<__attribute__((address_space(3))) u32*>(
        reinterpret_cast<uintptr_t>(s));
    __builtin_amdgcn_global_load_lds(gp, sp, 16, 0, 0);
}

#define BK 32

// LDS tile layout: rows of 64B (32 bf16). Swizzle: 16B slot ^= (row>>1)&3,
// i.e. addr ^= ((addr>>7)&3)<<4. Applied on global SOURCE at staging (LDS
// dest stays linear, per global_load_lds constraint) and on fragment reads.
// Verified R5: SQ_LDS_BANK_CONFLICT 4.2M -> 0.
__device__ __forceinline__ int swz(int a) { return a ^ (((a >> 7) & 3) << 4); }

template <int ROWS>
__device__ __forceinline__ void stage_tile(const u16* g, size_t krow_b, size_t kb0,
                                           u16* s, int t) {
#pragma unroll
    for (int rnd = 0; rnd < ROWS / 64; rnd++) {
        int o = t * 16 + rnd * 4096;
        int os = swz(o);
        int row = o >> 6, kb = os & 63;
        gload16((const char*)g + (size_t)row * krow_b + kb0 + kb, (char*)s + o);
    }
}

// C[M,N] = A[M,K]*B[N,K]^T (+ SPLIT: A_lo*B + A*B_lo), bf16 in, fp32 acc.
// K is the full row stride; each blockIdx.z chunk loops K/KCHUNKS of it.
// EPI 0: f32 store                           (q projection, fused split)
// EPI 1: silu -> bf16 store                  (up proj)
// EPI 2: chunk0: f32 store of acc+ext; chunk1: f32 store of acc to Cout2
template <int EPI, int TBM, int TBN, bool SPLIT, int KCHUNKS>
__global__ __launch_bounds__(256) void gemm_bt(
    const u16* __restrict__ A, const u16* __restrict__ Alo,
    const u16* __restrict__ B, const u16* __restrict__ Blo,
    void* __restrict__ Cout, void* __restrict__ Cout2,
    const float* __restrict__ ext, int M, int N, int K) {
    constexpr int NS = SPLIT ? 2 : 1;
    constexpr int WM = TBM / 2, WN = TBN / 2;
    constexpr int FM = WM / 16, FN = WN / 16;
    __shared__ u16 As[NS * TBM * BK];
    __shared__ u16 Bs[NS * TBN * BK];
    const int t = threadIdx.x;
    const int lane = t & 63;
    const int wave = t >> 6;
    const int wr = wave >> 1, wc = wave & 1;
    const int m0 = blockIdx.y * TBM;
    const int n0 = blockIdx.x * TBN;
    const int klen = K / KCHUNKS;
    const int koff = (KCHUNKS > 1) ? blockIdx.z * klen : 0;

    f32x4 acc[FM][FN];
#pragma unroll
    for (int i = 0; i < FM; i++)
#pragma unroll
        for (int j = 0; j < FN; j++) acc[i][j] = (f32x4){0.f, 0.f, 0.f, 0.f};

    const size_t krow = (size_t)K * 2;  // bytes per row
    const int ro = lane & 15;
    const int ko = (lane >> 4) * 16;  // byte offset into 64B row

    const u16* Ab = A + (size_t)m0 * K;
    const u16* Bb = B + (size_t)n0 * K;
    const u16* Alb = SPLIT ? Alo + (size_t)m0 * K : nullptr;
    const u16* Blb = SPLIT ? Blo + (size_t)n0 * K : nullptr;

    for (int k0 = koff; k0 < koff + klen; k0 += BK) {
        size_t kb0 = (size_t)k0 * 2;
        stage_tile<TBM>(Ab, krow, kb0, As, t);
        stage_tile<TBN>(Bb, krow, kb0, Bs, t);
        if (SPLIT) {
            stage_tile<TBM>(Alb, krow, kb0, As + TBM * BK, t);
            stage_tile<TBN>(Blb, krow, kb0, Bs + TBN * BK, t);
        }
        __syncthreads();
        bf16x8 fa[FM], fb[FN], fal[FM], fbl[FN];
#pragma unroll
        for (int i = 0; i < FM; i++) {
            int a = swz((wr * WM + i * 16 + ro) * 64 + ko);
            fa[i] = *reinterpret_cast<const bf16x8*>((const char*)As + a);
            if (SPLIT)
                fal[i] = *reinterpret_cast<const bf16x8*>((const char*)(As + TBM * BK) + a);
        }
#pragma unroll
        for (int j = 0; j < FN; j++) {
            int a = swz((wc * WN + j * 16 + ro) * 64 + ko);
            fb[j] = *reinterpret_cast<const bf16x8*>((const char*)Bs + a);
            if (SPLIT)
                fbl[j] = *reinterpret_cast<const bf16x8*>((const char*)(Bs + TBN * BK) + a);
        }
#pragma unroll
        for (int i = 0; i < FM; i++)
#pragma unroll
            for (int j = 0; j < FN; j++) {
                acc[i][j] = __builtin_amdgcn_mfma_f32_16x16x32_bf16(fa[i], fb[j],
                                                                    acc[i][j], 0, 0, 0);
                if (SPLIT) {
                    acc[i][j] = __builtin_amdgcn_mfma_f32_16x16x32_bf16(fa[i], fbl[j],
                                                                        acc[i][j], 0, 0, 0);
                    acc[i][j] = __builtin_amdgcn_mfma_f32_16x16x32_bf16(fal[i], fb[j],
                                                                        acc[i][j], 0, 0, 0);
                }
            }
        __syncthreads();
    }

#pragma unroll
    for (int i = 0; i < FM; i++)
#pragma unroll
        for (int j = 0; j < FN; j++) {
            int col = n0 + wc * WN + j * 16 + (lane & 15);
            int rbase = m0 + wr * WM + i * 16 + (lane >> 4) * 4;
#pragma unroll
            for (int r = 0; r < 4; r++) {
                int row = rbase + r;
                float v = acc[i][j][r];
                size_t off = (size_t)row * N + col;
                if (EPI == 0) {
                    ((float*)Cout)[off] = v;
                } else if (EPI == 1) {
                    float s = v / (1.f + __expf(-v));
                    ((u16*)Cout)[off] = f2bf(s);
                } else {
                    if (KCHUNKS == 1 || blockIdx.z == 0)
                        ((float*)Cout)[off] = v + ext[off];
                    else
                        ((float*)Cout2)[off] = v;
                }
            }
        }
}

// Rank of value v (lane l) among 64 values in LDS, JAX top_k tie order:
// rank = #{j: vj > v} + #{j < l: vj == v}. No cross-lane ops, 16 broadcast
// b128 reads, fully parallel.
__device__ __forceinline__ int rank64(const float* base, float v, int l) {
    const float4* gv = reinterpret_cast<const float4*>(base);
    int rank = 0;
#pragma unroll
    for (int n = 0; n < 16; n++) {
        float4 o = gv[n];
        int b = n * 4;
        rank += (o.x > v) || (o.x == v && (b + 0) < l);
        rank += (o.y > v) || (o.y == v && (b + 1) < l);
        rank += (o.z > v) || (o.z == v && (b + 2) < l);
        rank += (o.w > v) || (o.w == v && (b + 3) < l);
    }
    return rank;
}

// Per-token router: sims, rank-based top-8 per (p,h) group, rank-based
// cartesian top-8 per head (JAX tie semantics), softmax gates.
__global__ __launch_bounds__(512) void router(
    const float* __restrict__ Q, const float* __restrict__ keys,
    int* __restrict__ sidx_g, float* __restrict__ gate_g) {
    __shared__ float qs[QDIM];
    __shared__ float sims[QDIM];        // 8 groups x 64
    __shared__ float topv[8][TOPK];
    __shared__ int topi[8][TOPK];
    __shared__ float pv[NHEADS][64];    // cartesian pair-sums
    __shared__ float st8[NHEADS][TOPK];
    __shared__ int sid8[NHEADS][TOPK];

    const int tok = blockIdx.x;
    const int tid = threadIdx.x;
    const int w = tid >> 6, l = tid & 63;

    qs[tid] = Q[(size_t)tok * QDIM + tid];
    __syncthreads();

    {   // one sim per thread: c = p*256 + h*64 + k
        int c = tid;
        int p = c >> 8, rem = c & 255, h = rem >> 6, k = rem & 63;
        const float4* kr =
            reinterpret_cast<const float4*>(keys + (((h * NKEYS + k) * 2 + p) * 64));
        const float4* qr = reinterpret_cast<const float4*>(qs + p * 256 + h * 64);
        float s = 0.f;
#pragma unroll
        for (int n = 0; n < 16; n++) {
            float4 a = qr[n], b = kr[n];
            s += a.x * b.x + a.y * b.y + a.z * b.z + a.w * b.w;
        }
        sims[c] = s;  // group g = p*4+h at base g*64
    }
    __syncthreads();

    {   // phase A: wave w ranks its group's 64 sims
        float v = sims[w * 64 + l];
        int rank = rank64(sims + w * 64, v, l);
        if (rank < TOPK) { topv[w][rank] = v; topi[w][rank] = l; }
    }
    __syncthreads();

    if (w < NHEADS) {  // phase B: pair-sums (pos = i*8+j = l)
        pv[w][l] = topv[w][l >> 3] + topv[4 + w][l & 7];
    }
    __syncthreads();

    if (w < NHEADS) {  // rank 64 pair-sums, top-8 by (value desc, pos asc)
        float v = pv[w][l];
        int rank = rank64(pv[w], v, l);
        if (rank < TOPK) {
            st8[w][rank] = v;
            sid8[w][rank] = topi[w][l >> 3] * NKEYS + topi[4 + w][l & 7];
        }
    }
    __syncthreads();

    if (tid < NHEADS * TOPK) {  // softmax + output, one thread per (h, r)
        int h = tid >> 3, r = tid & 7;
        float m0 = st8[h][0];
        float s = 0.f;
#pragma unroll
        for (int i = 0; i < TOPK; i++) s += __expf(st8[h][i] - m0);
        size_t o = ((size_t)tok * NHEADS + h) * TOPK + r;
        sidx_g[o] = sid8[h][r];
        gate_g[o] = __expf(st8[h][r] - m0) / s;
    }
}

// Streaming expert gather, fp8-e4m3 tables: one token per 256-thread block.
// Dot phase: wave w -> experts 8w..8w+7 (16B/lane loads, all in flight).
// Acc phase: wave w -> output quarter w, 32 independent 4B/lane loads,
// direct global store.
__global__ __launch_bounds__(256) void expert_gather(
    const u16* __restrict__ hid_bf, const u32* __restrict__ de_f8,
    const u32* __restrict__ ue_f8, const int* __restrict__ sidx_g,
    const float* __restrict__ gate_g, float* __restrict__ expst) {
    __shared__ float wks[32];
    __shared__ int eids_s[32];

    const int tok = blockIdx.x;
    const int w = threadIdx.x >> 6, l = threadIdx.x & 63;

    {   // dot phase
        u16x8 hv[2];
        const u16* hrow = hid_bf + (size_t)tok * HDIM + l * 16;
        hv[0] = *reinterpret_cast<const u16x8*>(hrow);
        hv[1] = *reinterpret_cast<const u16x8*>(hrow + 8);
        float h16[16];
#pragma unroll
        for (int t2 = 0; t2 < 8; t2++) { h16[t2] = bf2f(hv[0][t2]); h16[8 + t2] = bf2f(hv[1][t2]); }
        int eid[8];
        float gt[8];
#pragma unroll
        for (int j = 0; j < 8; j++) {
            size_t o = (size_t)tok * 32 + w * 8 + j;
            eid[j] = sidx_g[o];
            gt[j] = gate_g[o];
        }
        u32x4 dv[8];
#pragma unroll
        for (int j = 0; j < 8; j++) {
            // row = 1024 fp8 bytes = 256 u32; lane slice l*16 bytes -> u32 idx l*4
            const u32x4* dr = reinterpret_cast<const u32x4*>(de_f8 + (size_t)eid[j] * 256 + l * 4);
            dv[j] = *dr;
        }
        float dot[8];
#pragma unroll
        for (int j = 0; j < 8; j++) {
            float s = 0.f;
#pragma unroll
            for (int w2 = 0; w2 < 4; w2++) {
                u32 word = dv[j][w2];
                s += h16[w2 * 4 + 0] * __builtin_amdgcn_cvt_f32_fp8(word, 0);
                s += h16[w2 * 4 + 1] * __builtin_amdgcn_cvt_f32_fp8(word, 1);
                s += h16[w2 * 4 + 2] * __builtin_amdgcn_cvt_f32_fp8(word, 2);
                s += h16[w2 * 4 + 3] * __builtin_amdgcn_cvt_f32_fp8(word, 3);
            }
            dot[j] = s;
        }
#pragma unroll
        for (int m = 32; m; m >>= 1)
#pragma unroll
            for (int j = 0; j < 8; j++) dot[j] += __shfl_xor(dot[j], m, 64);
#pragma unroll
        for (int j = 0; j < 8; j++)
            if (l == j) {
                float x = dot[j] * gt[j];
                wks[w * 8 + j] = x / (1.f + __expf(-x));
                eids_s[w * 8 + j] = eid[j];
            }
    }
    __syncthreads();

    {   // acc phase: wave w owns dims [w*256, (w+1)*256); 4 fp8 per lane
        float acc0 = 0.f, acc1 = 0.f, acc2 = 0.f, acc3 = 0.f;
        const u32* ubase = ue_f8 + w * 64 + l;
#pragma unroll
        for (int m = 0; m < 32; m++) {
            int e = eids_s[m];
            float wk = wks[m];
            u32 u = ubase[(size_t)e * 256];
            acc0 += wk * __builtin_amdgcn_cvt_f32_fp8(u, 0);
            acc1 += wk * __builtin_amdgcn_cvt_f32_fp8(u, 1);
            acc2 += wk * __builtin_amdgcn_cvt_f32_fp8(u, 2);
            acc3 += wk * __builtin_amdgcn_cvt_f32_fp8(u, 3);
        }
        float4 a4 = make_float4(acc0, acc1, acc2, acc3);
        *reinterpret_cast<float4*>(expst + (size_t)tok * HDIM + w * 256 + l * 4) = a4;
    }
}

extern "C" void kernel_launch(void* const* d_in, const int* in_sizes, int n_in,
                              void* d_out, int out_size, void* d_ws, size_t ws_size,
                              hipStream_t stream) {
    const float* hidden = (const float*)d_in[0];
    const float* W_up = (const float*)d_in[1];
    const float* W_down = (const float*)d_in[2];
    const float* W_q = (const float*)d_in[3];
    const float* keys = (const float*)d_in[4];
    const float* down_embed = (const float*)d_in[5];
    const float* up_embed = (const float*)d_in[6];
    float* out = (float*)d_out;

    char* ws = (char*)d_ws;
    size_t off = 0;
    auto alloc = [&](size_t bytes) {
        void* p = ws + off;
        off += (bytes + 255) & ~(size_t)255;
        return p;
    };
    u16* hid_hi = (u16*)alloc((size_t)TOKENS * HDIM * 2);
    // hid_lo (8.39 MB) + Qb (8.39 MB) are dead after router; the down-proj
    // K-chunk-1 partial (16.78 MB = TOKENS*HDIM*4) overlays them exactly.
    u16* hid_lo = (u16*)alloc((size_t)TOKENS * HDIM * 2);
    float* Qb = (float*)alloc((size_t)TOKENS * QDIM * 4);
    float* partial = (float*)hid_lo;
    u16* wq_hi = (u16*)alloc((size_t)QDIM * HDIM * 2);
    u16* wq_lo = (u16*)alloc((size_t)QDIM * HDIM * 2);
    u16* wup = (u16*)alloc((size_t)IDIM * HDIM * 2);
    u16* wdn = (u16*)alloc((size_t)HDIM * IDIM * 2);
    u16* act = (u16*)alloc((size_t)TOKENS * IDIM * 2);
    u32* de_f8 = (u32*)alloc((size_t)4096 * HDIM);
    u32* ue_f8 = (u32*)alloc((size_t)4096 * HDIM);
    float* expst = (float*)alloc((size_t)TOKENS * HDIM * 4);
    int* sidx_g = (int*)alloc((size_t)TOKENS * 32 * 4);
    float* gate_g = (float*)alloc((size_t)TOKENS * 32 * 4);

    cvt_all<<<(CVT_TOT + 255) / 256, 256, 0, stream>>>(
        hidden, W_q, W_up, W_down, down_embed, up_embed,
        hid_hi, hid_lo, wq_hi, wq_lo, wup, wdn, de_f8, ue_f8);

    dim3 blk(256);
    // q projection, fused split-bf16: hi*hi + hi*lo + lo*hi, 64x128 tile
    gemm_bt<0, 64, 128, true, 1><<<dim3(QDIM / 128, TOKENS / 64), blk, 0, stream>>>(
        hid_hi, hid_lo, wq_hi, wq_lo, Qb, nullptr, nullptr, TOKENS, QDIM, HDIM);

    router<<<TOKENS, 512, 0, stream>>>(Qb, keys, sidx_g, gate_g);
    expert_gather<<<TOKENS, 256, 0, stream>>>(hid_hi, de_f8, ue_f8, sidx_g, gate_g, expst);

    // up proj: 128x128 tile, grid 1024
    gemm_bt<1, 128, 128, false, 1><<<dim3(IDIM / 128, TOKENS / 128), blk, 0, stream>>>(
        hid_hi, nullptr, wup, nullptr, act, nullptr, nullptr, TOKENS, IDIM, HDIM);
    // down proj: 128x64 tile, K-split x2 -> grid (16,32,2)=1024 blocks
    gemm_bt<2, 128, 64, false, 2><<<dim3(HDIM / 64, TOKENS / 128, 2), blk, 0, stream>>>(
        act, nullptr, wdn, nullptr, out, partial, expst, TOKENS, HDIM, IDIM);
    reduce_add<<<(TOKENS * HDIM / 4 + 255) / 256, 256, 0, stream>>>(out, partial,
                                                                    TOKENS * HDIM / 4);
}

// Round 7
// 249.349 us; speedup vs baseline: 2.0902x; 1.1162x over previous
//
#include <hip/hip_runtime.h>

typedef unsigned short u16;
typedef unsigned int u32;

#define TOKENS 4096   // B*T
#define HDIM 1024
#define IDIM 4096
#define NHEADS 4
#define NKEYS 64
#define TOPK 8
#define QDIM 512      // 2 * NHEADS * 64

typedef __bf16 bf16x8 __attribute__((ext_vector_type(8)));
typedef float  f32x4  __attribute__((ext_vector_type(4)));
typedef u16    u16x8  __attribute__((ext_vector_type(8)));
typedef u16    u16x4  __attribute__((ext_vector_type(4)));
typedef u32    u32x4  __attribute__((ext_vector_type(4)));

__device__ __forceinline__ u16 f2bf(float f) {
    u32 u = __float_as_uint(f);
    u += 0x7fffu + ((u >> 16) & 1u);   // RNE
    return (u16)(u >> 16);
}
__device__ __forceinline__ float bf2f(u16 h) { return __uint_as_float(((u32)h) << 16); }

// ---- fused fp32->bf16 / fp32->fp8 conversion over all tensors ----
#define H_N4   1048576   // TOKENS*HDIM/4   (hi+lo)
#define WUP_N4 1048576
#define WDN_N4 1048576
#define DE_N4  1048576
#define UE_N4  1048576
#define CVT_TOT (H_N4 + WUP_N4 + WDN_N4 + DE_N4 + UE_N4)

__device__ __forceinline__ void cvt1(const float* in, u16* hi, u16* lo, int i) {
    float4 v = reinterpret_cast<const float4*>(in)[i];
    float vf[4] = {v.x, v.y, v.z, v.w};
    ushort4 h;
    u16 hh[4];
#pragma unroll
    for (int j = 0; j < 4; j++) hh[j] = f2bf(vf[j]);
    h.x = hh[0]; h.y = hh[1]; h.z = hh[2]; h.w = hh[3];
    reinterpret_cast<ushort4*>(hi)[i] = h;
    if (lo) {
        ushort4 l4;
        u16 ll[4];
#pragma unroll
        for (int j = 0; j < 4; j++) ll[j] = f2bf(vf[j] - bf2f(hh[j]));
        l4.x = ll[0]; l4.y = ll[1]; l4.z = ll[2]; l4.w = ll[3];
        reinterpret_cast<ushort4*>(lo)[i] = l4;
    }
}

__device__ __forceinline__ void cvt1_f8(const float* in, u32* out8, int i) {
    float4 v = reinterpret_cast<const float4*>(in)[i];
    u32 w = __builtin_amdgcn_cvt_pk_fp8_f32(v.x, v.y, 0u, false);
    w = __builtin_amdgcn_cvt_pk_fp8_f32(v.z, v.w, w, true);
    out8[i] = w;
}

__global__ __launch_bounds__(256) void cvt_all(
    const float* __restrict__ hidden, const float* __restrict__ W_up,
    const float* __restrict__ W_down, const float* __restrict__ de,
    const float* __restrict__ ue,
    u16* __restrict__ hid_hi, u16* __restrict__ hid_lo,
    u16* __restrict__ wup, u16* __restrict__ wdn,
    u32* __restrict__ de_f8, u32* __restrict__ ue_f8) {
    int i = blockIdx.x * 256 + threadIdx.x;
    if (i >= CVT_TOT) return;
    if (i < H_N4) { cvt1(hidden, hid_hi, hid_lo, i); return; }
    i -= H_N4;
    if (i < WUP_N4) { cvt1(W_up, wup, nullptr, i); return; }
    i -= WUP_N4;
    if (i < WDN_N4) { cvt1(W_down, wdn, nullptr, i); return; }
    i -= WDN_N4;
    if (i < DE_N4) { cvt1_f8(de, de_f8, i); return; }
    i -= DE_N4;
    cvt1_f8(ue, ue_f8, i);
}

// Weff[(p*4+h)*64+k][d] = sum_n keys[h][k][p][n] * Wq[p*256+h*64+n][d],
// fp32 accumulate, split hi/lo bf16 output. Folds the product-key sim into
// the query projection: sim = hid @ Weff^T (selection-exact to ~1e-7).
// Grid: 64 blocks = 8 groups x 8 d-slices of 128. 256 threads.
__global__ __launch_bounds__(256) void weff_kernel(
    const float* __restrict__ keys, const float* __restrict__ Wq,
    u16* __restrict__ weff_hi, u16* __restrict__ weff_lo) {
    __shared__ float kk[64][65];      // padded: bank = (k+n)%32, conflict-free
    __shared__ float wq_s[64][128];

    const int g = blockIdx.x >> 3, ds = blockIdx.x & 7;
    const int p = g >> 2, h = g & 3;
    const int d0 = ds * 128;
    const int t = threadIdx.x;
    const int base = p * 256 + h * 64;  // Wq row base for this group

    {   // stage keys group [64 k][64 n]
        int k = t >> 2, part = t & 3;
        const float* krow = keys + (((size_t)(h * NKEYS + k) * 2 + p) * 64);
#pragma unroll
        for (int j = 0; j < 4; j++) {
            int n0 = part * 16 + j * 4;
            float4 v = *reinterpret_cast<const float4*>(krow + n0);
            kk[k][n0 + 0] = v.x; kk[k][n0 + 1] = v.y;
            kk[k][n0 + 2] = v.z; kk[k][n0 + 3] = v.w;
        }
    }
    {   // stage Wq slice [64 n][128 d]
        int n = t >> 2, dpart = t & 3;
        const float* wrow = Wq + (size_t)(base + n) * HDIM + d0;
#pragma unroll
        for (int j = 0; j < 8; j++) {
            int dd = dpart * 32 + j * 4;
            float4 v = *reinterpret_cast<const float4*>(wrow + dd);
            *reinterpret_cast<float4*>(&wq_s[n][dd]) = v;
        }
    }
    __syncthreads();

    // thread: k = t&63, dq = t>>6 -> 32 d-columns [dq*32, dq*32+32)
    const int k = t & 63, dq = t >> 6;
    float acc[32];
#pragma unroll
    for (int i = 0; i < 32; i++) acc[i] = 0.f;
    for (int n = 0; n < 64; n++) {
        float kv = kk[k][n];
        const float4* wrow = reinterpret_cast<const float4*>(&wq_s[n][dq * 32]);
#pragma unroll
        for (int j = 0; j < 8; j++) {
            float4 w4 = wrow[j];  // broadcast (same addr across lanes)
            acc[j * 4 + 0] += kv * w4.x; acc[j * 4 + 1] += kv * w4.y;
            acc[j * 4 + 2] += kv * w4.z; acc[j * 4 + 3] += kv * w4.w;
        }
    }
    size_t ro = (size_t)(g * 64 + k) * HDIM + d0 + dq * 32;
#pragma unroll
    for (int j = 0; j < 8; j++) {
        ushort4 hh, ll;
        u16 hv[4], lv[4];
#pragma unroll
        for (int i = 0; i < 4; i++) {
            float a = acc[j * 4 + i];
            hv[i] = f2bf(a);
            lv[i] = f2bf(a - bf2f(hv[i]));
        }
        hh.x = hv[0]; hh.y = hv[1]; hh.z = hv[2]; hh.w = hv[3];
        ll.x = lv[0]; ll.y = lv[1]; ll.z = lv[2]; ll.w = lv[3];
        *reinterpret_cast<ushort4*>(weff_hi + ro + j * 4) = hh;
        *reinterpret_cast<ushort4*>(weff_lo + ro + j * 4) = ll;
    }
}

// out += partial (after both K-chunks of down proj completed)
__global__ __launch_bounds__(256) void reduce_add(float* __restrict__ out,
                                                  const float* __restrict__ p, int n4) {
    int i = blockIdx.x * 256 + threadIdx.x;
    if (i >= n4) return;
    float4 a = reinterpret_cast<const float4*>(out)[i];
    float4 b = reinterpret_cast<const float4*>(p)[i];
    a.x += b.x; a.y += b.y; a.z += b.z; a.w += b.w;
    reinterpret_cast<float4*>(out)[i] = a;
}

__device__ __forceinline__ void gload16(const void* g, void* s) {
    auto gp = reinterpret_cast<const __attribute__((address_space(1))) u32*>(
        reinterpret_cast<uintptr_t>(g));
    auto sp = reinterpret_cast<__attribute__((address_space(3))) u32*>(
        reinterpret_cast<uintptr_t>(s));
    __builtin_amdgcn_global_load_lds(gp, sp, 16, 0, 0);
}

#define BK 32

// LDS tile layout: rows of 64B (32 bf16). Swizzle: 16B slot ^= (row>>1)&3.
// Verified R5: SQ_LDS_BANK_CONFLICT 4.2M -> 0.
__device__ __forceinline__ int swz(int a) { return a ^ (((a >> 7) & 3) << 4); }

template <int ROWS>
__device__ __forceinline__ void stage_tile(const u16* g, size_t krow_b, size_t kb0,
                                           u16* s, int t) {
#pragma unroll
    for (int rnd = 0; rnd < ROWS / 64; rnd++) {
        int o = t * 16 + rnd * 4096;
        int os = swz(o);
        int row = o >> 6, kb = os & 63;
        gload16((const char*)g + (size_t)row * krow_b + kb0 + kb, (char*)s + o);
    }
}

// C[M,N] = A[M,K]*B[N,K]^T (+ SPLIT: A_lo*B + A*B_lo), bf16 in, fp32 acc.
template <int EPI, int TBM, int TBN, bool SPLIT, int KCHUNKS>
__global__ __launch_bounds__(256) void gemm_bt(
    const u16* __restrict__ A, const u16* __restrict__ Alo,
    const u16* __restrict__ B, const u16* __restrict__ Blo,
    void* __restrict__ Cout, void* __restrict__ Cout2,
    const float* __restrict__ ext, int M, int N, int K) {
    constexpr int NS = SPLIT ? 2 : 1;
    constexpr int WM = TBM / 2, WN = TBN / 2;
    constexpr int FM = WM / 16, FN = WN / 16;
    __shared__ u16 As[NS * TBM * BK];
    __shared__ u16 Bs[NS * TBN * BK];
    const int t = threadIdx.x;
    const int lane = t & 63;
    const int wave = t >> 6;
    const int wr = wave >> 1, wc = wave & 1;
    const int m0 = blockIdx.y * TBM;
    const int n0 = blockIdx.x * TBN;
    const int klen = K / KCHUNKS;
    const int koff = (KCHUNKS > 1) ? blockIdx.z * klen : 0;

    f32x4 acc[FM][FN];
#pragma unroll
    for (int i = 0; i < FM; i++)
#pragma unroll
        for (int j = 0; j < FN; j++) acc[i][j] = (f32x4){0.f, 0.f, 0.f, 0.f};

    const size_t krow = (size_t)K * 2;  // bytes per row
    const int ro = lane & 15;
    const int ko = (lane >> 4) * 16;  // byte offset into 64B row

    const u16* Ab = A + (size_t)m0 * K;
    const u16* Bb = B + (size_t)n0 * K;
    const u16* Alb = SPLIT ? Alo + (size_t)m0 * K : nullptr;
    const u16* Blb = SPLIT ? Blo + (size_t)n0 * K : nullptr;

    for (int k0 = koff; k0 < koff + klen; k0 += BK) {
        size_t kb0 = (size_t)k0 * 2;
        stage_tile<TBM>(Ab, krow, kb0, As, t);
        stage_tile<TBN>(Bb, krow, kb0, Bs, t);
        if (SPLIT) {
            stage_tile<TBM>(Alb, krow, kb0, As + TBM * BK, t);
            stage_tile<TBN>(Blb, krow, kb0, Bs + TBN * BK, t);
        }
        __syncthreads();
        bf16x8 fa[FM], fb[FN], fal[FM], fbl[FN];
#pragma unroll
        for (int i = 0; i < FM; i++) {
            int a = swz((wr * WM + i * 16 + ro) * 64 + ko);
            fa[i] = *reinterpret_cast<const bf16x8*>((const char*)As + a);
            if (SPLIT)
                fal[i] = *reinterpret_cast<const bf16x8*>((const char*)(As + TBM * BK) + a);
        }
#pragma unroll
        for (int j = 0; j < FN; j++) {
            int a = swz((wc * WN + j * 16 + ro) * 64 + ko);
            fb[j] = *reinterpret_cast<const bf16x8*>((const char*)Bs + a);
            if (SPLIT)
                fbl[j] = *reinterpret_cast<const bf16x8*>((const char*)(Bs + TBN * BK) + a);
        }
#pragma unroll
        for (int i = 0; i < FM; i++)
#pragma unroll
            for (int j = 0; j < FN; j++) {
                acc[i][j] = __builtin_amdgcn_mfma_f32_16x16x32_bf16(fa[i], fb[j],
                                                                    acc[i][j], 0, 0, 0);
                if (SPLIT) {
                    acc[i][j] = __builtin_amdgcn_mfma_f32_16x16x32_bf16(fa[i], fbl[j],
                                                                        acc[i][j], 0, 0, 0);
                    acc[i][j] = __builtin_amdgcn_mfma_f32_16x16x32_bf16(fal[i], fb[j],
                                                                        acc[i][j], 0, 0, 0);
                }
            }
        __syncthreads();
    }

#pragma unroll
    for (int i = 0; i < FM; i++)
#pragma unroll
        for (int j = 0; j < FN; j++) {
            int col = n0 + wc * WN + j * 16 + (lane & 15);
            int rbase = m0 + wr * WM + i * 16 + (lane >> 4) * 4;
#pragma unroll
            for (int r = 0; r < 4; r++) {
                int row = rbase + r;
                float v = acc[i][j][r];
                size_t off = (size_t)row * N + col;
                if (EPI == 0) {
                    ((float*)Cout)[off] = v;
                } else if (EPI == 1) {
                    float s = v / (1.f + __expf(-v));
                    ((u16*)Cout)[off] = f2bf(s);
                } else {
                    if (KCHUNKS == 1 || blockIdx.z == 0)
                        ((float*)Cout)[off] = v + ext[off];
                    else
                        ((float*)Cout2)[off] = v;
                }
            }
        }
}

// Rank of value v (lane l) among 64 values in LDS, JAX top_k tie order.
__device__ __forceinline__ int rank64(const float* base, float v, int l) {
    const float4* gv = reinterpret_cast<const float4*>(base);
    int rank = 0;
#pragma unroll
    for (int n = 0; n < 16; n++) {
        float4 o = gv[n];
        int b = n * 4;
        rank += (o.x > v) || (o.x == v && (b + 0) < l);
        rank += (o.y > v) || (o.y == v && (b + 1) < l);
        rank += (o.z > v) || (o.z == v && (b + 2) < l);
        rank += (o.w > v) || (o.w == v && (b + 3) < l);
    }
    return rank;
}

// Per-token router: loads precomputed sims (= hid @ Weff^T), rank-based
// top-8 per (p,h) group, rank-based cartesian top-8 per head, softmax gates.
__global__ __launch_bounds__(512) void router(
    const float* __restrict__ Simb,
    int* __restrict__ sidx_g, float* __restrict__ gate_g) {
    __shared__ float sims[QDIM];        // 8 groups x 64
    __shared__ float topv[8][TOPK];
    __shared__ int topi[8][TOPK];
    __shared__ float pv[NHEADS][64];    // cartesian pair-sums
    __shared__ float st8[NHEADS][TOPK];
    __shared__ int sid8[NHEADS][TOPK];

    const int tok = blockIdx.x;
    const int tid = threadIdx.x;
    const int w = tid >> 6, l = tid & 63;

    sims[tid] = Simb[(size_t)tok * QDIM + tid];
    __syncthreads();

    {   // phase A: wave w ranks its group's 64 sims
        float v = sims[w * 64 + l];
        int rank = rank64(sims + w * 64, v, l);
        if (rank < TOPK) { topv[w][rank] = v; topi[w][rank] = l; }
    }
    __syncthreads();

    if (w < NHEADS) {  // phase B: pair-sums (pos = i*8+j = l)
        pv[w][l] = topv[w][l >> 3] + topv[4 + w][l & 7];
    }
    __syncthreads();

    if (w < NHEADS) {  // rank 64 pair-sums, top-8 by (value desc, pos asc)
        float v = pv[w][l];
        int rank = rank64(pv[w], v, l);
        if (rank < TOPK) {
            st8[w][rank] = v;
            sid8[w][rank] = topi[w][l >> 3] * NKEYS + topi[4 + w][l & 7];
        }
    }
    __syncthreads();

    if (tid < NHEADS * TOPK) {  // softmax + output, one thread per (h, r)
        int h = tid >> 3, r = tid & 7;
        float m0 = st8[h][0];
        float s = 0.f;
#pragma unroll
        for (int i = 0; i < TOPK; i++) s += __expf(st8[h][i] - m0);
        size_t o = ((size_t)tok * NHEADS + h) * TOPK + r;
        sidx_g[o] = sid8[h][r];
        gate_g[o] = __expf(st8[h][r] - m0) / s;
    }
}

// Streaming expert gather, fp8-e4m3 tables: one token per 256-thread block.
__global__ __launch_bounds__(256) void expert_gather(
    const u16* __restrict__ hid_bf, const u32* __restrict__ de_f8,
    const u32* __restrict__ ue_f8, const int* __restrict__ sidx_g,
    const float* __restrict__ gate_g, float* __restrict__ expst) {
    __shared__ float wks[32];
    __shared__ int eids_s[32];

    const int tok = blockIdx.x;
    const int w = threadIdx.x >> 6, l = threadIdx.x & 63;

    {   // dot phase
        u16x8 hv[2];
        const u16* hrow = hid_bf + (size_t)tok * HDIM + l * 16;
        hv[0] = *reinterpret_cast<const u16x8*>(hrow);
        hv[1] = *reinterpret_cast<const u16x8*>(hrow + 8);
        float h16[16];
#pragma unroll
        for (int t2 = 0; t2 < 8; t2++) { h16[t2] = bf2f(hv[0][t2]); h16[8 + t2] = bf2f(hv[1][t2]); }
        int eid[8];
        float gt[8];
#pragma unroll
        for (int j = 0; j < 8; j++) {
            size_t o = (size_t)tok * 32 + w * 8 + j;
            eid[j] = sidx_g[o];
            gt[j] = gate_g[o];
        }
        u32x4 dv[8];
#pragma unroll
        for (int j = 0; j < 8; j++) {
            const u32x4* dr = reinterpret_cast<const u32x4*>(de_f8 + (size_t)eid[j] * 256 + l * 4);
            dv[j] = *dr;
        }
        float dot[8];
#pragma unroll
        for (int j = 0; j < 8; j++) {
            float s = 0.f;
#pragma unroll
            for (int w2 = 0; w2 < 4; w2++) {
                u32 word = dv[j][w2];
                s += h16[w2 * 4 + 0] * __builtin_amdgcn_cvt_f32_fp8(word, 0);
                s += h16[w2 * 4 + 1] * __builtin_amdgcn_cvt_f32_fp8(word, 1);
                s += h16[w2 * 4 + 2] * __builtin_amdgcn_cvt_f32_fp8(word, 2);
                s += h16[w2 * 4 + 3] * __builtin_amdgcn_cvt_f32_fp8(word, 3);
            }
            dot[j] = s;
        }
#pragma unroll
        for (int m = 32; m; m >>= 1)
#pragma unroll
            for (int j = 0; j < 8; j++) dot[j] += __shfl_xor(dot[j], m, 64);
#pragma unroll
        for (int j = 0; j < 8; j++)
            if (l == j) {
                float x = dot[j] * gt[j];
                wks[w * 8 + j] = x / (1.f + __expf(-x));
                eids_s[w * 8 + j] = eid[j];
            }
    }
    __syncthreads();

    {   // acc phase: wave w owns dims [w*256, (w+1)*256); 4 fp8 per lane
        float acc0 = 0.f, acc1 = 0.f, acc2 = 0.f, acc3 = 0.f;
        const u32* ubase = ue_f8 + w * 64 + l;
#pragma unroll
        for (int m = 0; m < 32; m++) {
            int e = eids_s[m];
            float wk = wks[m];
            u32 u = ubase[(size_t)e * 256];
            acc0 += wk * __builtin_amdgcn_cvt_f32_fp8(u, 0);
            acc1 += wk * __builtin_amdgcn_cvt_f32_fp8(u, 1);
            acc2 += wk * __builtin_amdgcn_cvt_f32_fp8(u, 2);
            acc3 += wk * __builtin_amdgcn_cvt_f32_fp8(u, 3);
        }
        float4 a4 = make_float4(acc0, acc1, acc2, acc3);
        *reinterpret_cast<float4*>(expst + (size_t)tok * HDIM + w * 256 + l * 4) = a4;
    }
}

extern "C" void kernel_launch(void* const* d_in, const int* in_sizes, int n_in,
                              void* d_out, int out_size, void* d_ws, size_t ws_size,
                              hipStream_t stream) {
    const float* hidden = (const float*)d_in[0];
    const float* W_up = (const float*)d_in[1];
    const float* W_down = (const float*)d_in[2];
    const float* W_q = (const float*)d_in[3];
    const float* keys = (const float*)d_in[4];
    const float* down_embed = (const float*)d_in[5];
    const float* up_embed = (const float*)d_in[6];
    float* out = (float*)d_out;

    char* ws = (char*)d_ws;
    size_t off = 0;
    auto alloc = [&](size_t bytes) {
        void* p = ws + off;
        off += (bytes + 255) & ~(size_t)255;
        return p;
    };
    u16* hid_hi = (u16*)alloc((size_t)TOKENS * HDIM * 2);
    // hid_lo (8.39 MB) + Simb (8.39 MB) are dead after router; the down-proj
    // K-chunk-1 partial (16.78 MB) overlays them.
    u16* hid_lo = (u16*)alloc((size_t)TOKENS * HDIM * 2);
    float* Simb = (float*)alloc((size_t)TOKENS * QDIM * 4);
    float* partial = (float*)hid_lo;
    u16* weff_hi = (u16*)alloc((size_t)QDIM * HDIM * 2);
    u16* weff_lo = (u16*)alloc((size_t)QDIM * HDIM * 2);
    u16* wup = (u16*)alloc((size_t)IDIM * HDIM * 2);
    u16* wdn = (u16*)alloc((size_t)HDIM * IDIM * 2);
    u16* act = (u16*)alloc((size_t)TOKENS * IDIM * 2);
    u32* de_f8 = (u32*)alloc((size_t)4096 * HDIM);
    u32* ue_f8 = (u32*)alloc((size_t)4096 * HDIM);
    float* expst = (float*)alloc((size_t)TOKENS * HDIM * 4);
    int* sidx_g = (int*)alloc((size_t)TOKENS * 32 * 4);
    float* gate_g = (float*)alloc((size_t)TOKENS * 32 * 4);

    cvt_all<<<(CVT_TOT + 255) / 256, 256, 0, stream>>>(
        hidden, W_up, W_down, down_embed, up_embed,
        hid_hi, hid_lo, wup, wdn, de_f8, ue_f8);
    weff_kernel<<<64, 256, 0, stream>>>(keys, W_q, weff_hi, weff_lo);

    dim3 blk(256);
    // sim projection (q-proj with keys folded in), split-bf16, 64x128 tile
    gemm_bt<0, 64, 128, true, 1><<<dim3(QDIM / 128, TOKENS / 64), blk, 0, stream>>>(
        hid_hi, hid_lo, weff_hi, weff_lo, Simb, nullptr, nullptr, TOKENS, QDIM, HDIM);

    router<<<TOKENS, 512, 0, stream>>>(Simb, sidx_g, gate_g);
    expert_gather<<<TOKENS, 256, 0, stream>>>(hid_hi, de_f8, ue_f8, sidx_g, gate_g, expst);

    // up proj: 128x128 tile, grid 1024
    gemm_bt<1, 128, 128, false, 1><<<dim3(IDIM / 128, TOKENS / 128), blk, 0, stream>>>(
        hid_hi, nullptr, wup, nullptr, act, nullptr, nullptr, TOKENS, IDIM, HDIM);
    // down proj: 128x64 tile, K-split x2 -> grid (16,32,2)=1024 blocks
    gemm_bt<2, 128, 64, false, 2><<<dim3(HDIM / 64, TOKENS / 128, 2), blk, 0, stream>>>(
        act, nullptr, wdn, nullptr, out, partial, expst, TOKENS, HDIM, IDIM);
    reduce_add<<<(TOKENS * HDIM / 4 + 255) / 256, 256, 0, stream>>>(out, partial,
                                                                    TOKENS * HDIM / 4);
}

// Round 8
// 235.891 us; speedup vs baseline: 2.2094x; 1.0570x over previous
//
#include <hip/hip_runtime.h>

typedef unsigned short u16;
typedef unsigned int u32;

#define TOKENS 4096   // B*T
#define HDIM 1024
#define IDIM 4096
#define NHEADS 4
#define NKEYS 64
#define TOPK 8
#define QDIM 512      // 2 * NHEADS * 64

typedef __bf16 bf16x8 __attribute__((ext_vector_type(8)));
typedef float  f32x4  __attribute__((ext_vector_type(4)));
typedef u16    u16x8  __attribute__((ext_vector_type(8)));
typedef u16    u16x4  __attribute__((ext_vector_type(4)));
typedef u32    u32x4  __attribute__((ext_vector_type(4)));

__device__ __forceinline__ u16 f2bf(float f) {
    u32 u = __float_as_uint(f);
    u += 0x7fffu + ((u >> 16) & 1u);   // RNE
    return (u16)(u >> 16);
}
__device__ __forceinline__ float bf2f(u16 h) { return __uint_as_float(((u32)h) << 16); }

// ---- fused fp32->bf16 / fp32->fp8 conversion over all tensors ----
#define H_N4   1048576   // TOKENS*HDIM/4   (hi+lo)
#define WUP_N4 1048576
#define WDN_N4 1048576
#define DE_N4  1048576
#define UE_N4  1048576
#define CVT_TOT (H_N4 + WUP_N4 + WDN_N4 + DE_N4 + UE_N4)

__device__ __forceinline__ void cvt1(const float* in, u16* hi, u16* lo, int i) {
    float4 v = reinterpret_cast<const float4*>(in)[i];
    float vf[4] = {v.x, v.y, v.z, v.w};
    ushort4 h;
    u16 hh[4];
#pragma unroll
    for (int j = 0; j < 4; j++) hh[j] = f2bf(vf[j]);
    h.x = hh[0]; h.y = hh[1]; h.z = hh[2]; h.w = hh[3];
    reinterpret_cast<ushort4*>(hi)[i] = h;
    if (lo) {
        ushort4 l4;
        u16 ll[4];
#pragma unroll
        for (int j = 0; j < 4; j++) ll[j] = f2bf(vf[j] - bf2f(hh[j]));
        l4.x = ll[0]; l4.y = ll[1]; l4.z = ll[2]; l4.w = ll[3];
        reinterpret_cast<ushort4*>(lo)[i] = l4;
    }
}

__device__ __forceinline__ void cvt1_f8(const float* in, u32* out8, int i) {
    float4 v = reinterpret_cast<const float4*>(in)[i];
    u32 w = __builtin_amdgcn_cvt_pk_fp8_f32(v.x, v.y, 0u, false);
    w = __builtin_amdgcn_cvt_pk_fp8_f32(v.z, v.w, w, true);
    out8[i] = w;
}

__global__ __launch_bounds__(256) void cvt_all(
    const float* __restrict__ hidden, const float* __restrict__ W_up,
    const float* __restrict__ W_down, const float* __restrict__ de,
    const float* __restrict__ ue,
    u16* __restrict__ hid_hi, u16* __restrict__ hid_lo,
    u16* __restrict__ wup, u16* __restrict__ wdn,
    u32* __restrict__ de_f8, u32* __restrict__ ue_f8) {
    int i = blockIdx.x * 256 + threadIdx.x;
    if (i >= CVT_TOT) return;
    if (i < H_N4) { cvt1(hidden, hid_hi, hid_lo, i); return; }
    i -= H_N4;
    if (i < WUP_N4) { cvt1(W_up, wup, nullptr, i); return; }
    i -= WUP_N4;
    if (i < WDN_N4) { cvt1(W_down, wdn, nullptr, i); return; }
    i -= WDN_N4;
    if (i < DE_N4) { cvt1_f8(de, de_f8, i); return; }
    i -= DE_N4;
    cvt1_f8(ue, ue_f8, i);
}

// Weff[(p*4+h)*64+k][d] = sum_n keys[h][k][p][n] * Wq[p*256+h*64+n][d],
// fp32 accumulate, split hi/lo bf16 output. Folds the product-key sim into
// the query projection: sim = hid @ Weff^T (selection-exact to ~1e-7).
__global__ __launch_bounds__(256) void weff_kernel(
    const float* __restrict__ keys, const float* __restrict__ Wq,
    u16* __restrict__ weff_hi, u16* __restrict__ weff_lo) {
    __shared__ float kk[64][65];
    __shared__ float wq_s[64][128];

    const int g = blockIdx.x >> 3, ds = blockIdx.x & 7;
    const int p = g >> 2, h = g & 3;
    const int d0 = ds * 128;
    const int t = threadIdx.x;
    const int base = p * 256 + h * 64;

    {
        int k = t >> 2, part = t & 3;
        const float* krow = keys + (((size_t)(h * NKEYS + k) * 2 + p) * 64);
#pragma unroll
        for (int j = 0; j < 4; j++) {
            int n0 = part * 16 + j * 4;
            float4 v = *reinterpret_cast<const float4*>(krow + n0);
            kk[k][n0 + 0] = v.x; kk[k][n0 + 1] = v.y;
            kk[k][n0 + 2] = v.z; kk[k][n0 + 3] = v.w;
        }
    }
    {
        int n = t >> 2, dpart = t & 3;
        const float* wrow = Wq + (size_t)(base + n) * HDIM + d0;
#pragma unroll
        for (int j = 0; j < 8; j++) {
            int dd = dpart * 32 + j * 4;
            float4 v = *reinterpret_cast<const float4*>(wrow + dd);
            *reinterpret_cast<float4*>(&wq_s[n][dd]) = v;
        }
    }
    __syncthreads();

    const int k = t & 63, dq = t >> 6;
    float acc[32];
#pragma unroll
    for (int i = 0; i < 32; i++) acc[i] = 0.f;
    for (int n = 0; n < 64; n++) {
        float kv = kk[k][n];
        const float4* wrow = reinterpret_cast<const float4*>(&wq_s[n][dq * 32]);
#pragma unroll
        for (int j = 0; j < 8; j++) {
            float4 w4 = wrow[j];
            acc[j * 4 + 0] += kv * w4.x; acc[j * 4 + 1] += kv * w4.y;
            acc[j * 4 + 2] += kv * w4.z; acc[j * 4 + 3] += kv * w4.w;
        }
    }
    size_t ro = (size_t)(g * 64 + k) * HDIM + d0 + dq * 32;
#pragma unroll
    for (int j = 0; j < 8; j++) {
        ushort4 hh, ll;
        u16 hv[4], lv[4];
#pragma unroll
        for (int i = 0; i < 4; i++) {
            float a = acc[j * 4 + i];
            hv[i] = f2bf(a);
            lv[i] = f2bf(a - bf2f(hv[i]));
        }
        hh.x = hv[0]; hh.y = hv[1]; hh.z = hv[2]; hh.w = hv[3];
        ll.x = lv[0]; ll.y = lv[1]; ll.z = lv[2]; ll.w = lv[3];
        *reinterpret_cast<ushort4*>(weff_hi + ro + j * 4) = hh;
        *reinterpret_cast<ushort4*>(weff_lo + ro + j * 4) = ll;
    }
}

// out += partial (after both K-chunks of down proj completed)
__global__ __launch_bounds__(256) void reduce_add(float* __restrict__ out,
                                                  const float* __restrict__ p, int n4) {
    int i = blockIdx.x * 256 + threadIdx.x;
    if (i >= n4) return;
    float4 a = reinterpret_cast<const float4*>(out)[i];
    float4 b = reinterpret_cast<const float4*>(p)[i];
    a.x += b.x; a.y += b.y; a.z += b.z; a.w += b.w;
    reinterpret_cast<float4*>(out)[i] = a;
}

__device__ __forceinline__ void gload16(const void* g, void* s) {
    auto gp = reinterpret_cast<const __attribute__((address_space(1))) u32*>(
        reinterpret_cast<uintptr_t>(g));
    auto sp = reinterpret_cast<__attribute__((address_space(3))) u32*>(
        reinterpret_cast<uintptr_t>(s));
    __builtin_amdgcn_global_load_lds(gp, sp, 16, 0, 0);
}

#define BK 32

// LDS tile layout: rows of 64B (32 bf16). Swizzle: 16B slot ^= (row>>1)&3.
// Verified R5: SQ_LDS_BANK_CONFLICT 4.2M -> 0.
__device__ __forceinline__ int swz(int a) { return a ^ (((a >> 7) & 3) << 4); }

template <int ROWS>
__device__ __forceinline__ void stage_tile(const u16* g, size_t krow_b, size_t kb0,
                                           u16* s, int t) {
#pragma unroll
    for (int rnd = 0; rnd < ROWS / 64; rnd++) {
        int o = t * 16 + rnd * 4096;
        int os = swz(o);
        int row = o >> 6, kb = os & 63;
        gload16((const char*)g + (size_t)row * krow_b + kb0 + kb, (char*)s + o);
    }
}

// C[M,N] = A[M,K]*B[N,K]^T (+ SPLIT: A_lo*B + A*B_lo), bf16 in, fp32 acc.
// 2-phase pipelined (T3-minimum): double-buffered LDS; per K-step issue
// STAGE(t+1) BEFORE compute(t); ONE __syncthreads per step (its built-in
// vmcnt(0)/lgkmcnt(0) drain covers both the prefetch and buffer reuse).
template <int EPI, int TBM, int TBN, bool SPLIT, int KCHUNKS>
__global__ __launch_bounds__(256) void gemm_bt(
    const u16* __restrict__ A, const u16* __restrict__ Alo,
    const u16* __restrict__ B, const u16* __restrict__ Blo,
    void* __restrict__ Cout, void* __restrict__ Cout2,
    const float* __restrict__ ext, int M, int N, int K) {
    constexpr int NS = SPLIT ? 2 : 1;
    constexpr int WM = TBM / 2, WN = TBN / 2;
    constexpr int FM = WM / 16, FN = WN / 16;
    constexpr int ASZ = NS * TBM * BK;
    constexpr int BSZ = NS * TBN * BK;
    __shared__ u16 As[2][ASZ];
    __shared__ u16 Bs[2][BSZ];
    const int t = threadIdx.x;
    const int lane = t & 63;
    const int wave = t >> 6;
    const int wr = wave >> 1, wc = wave & 1;
    const int m0 = blockIdx.y * TBM;
    const int n0 = blockIdx.x * TBN;
    const int klen = K / KCHUNKS;
    const int koff = (KCHUNKS > 1) ? blockIdx.z * klen : 0;

    f32x4 acc[FM][FN];
#pragma unroll
    for (int i = 0; i < FM; i++)
#pragma unroll
        for (int j = 0; j < FN; j++) acc[i][j] = (f32x4){0.f, 0.f, 0.f, 0.f};

    const size_t krow = (size_t)K * 2;  // bytes per row
    const int ro = lane & 15;
    const int ko = (lane >> 4) * 16;  // byte offset into 64B row

    const u16* Ab = A + (size_t)m0 * K;
    const u16* Bb = B + (size_t)n0 * K;
    const u16* Alb = SPLIT ? Alo + (size_t)m0 * K : nullptr;
    const u16* Blb = SPLIT ? Blo + (size_t)n0 * K : nullptr;

    auto stage_all = [&](int b, int k0) {
        size_t kb0 = (size_t)k0 * 2;
        stage_tile<TBM>(Ab, krow, kb0, As[b], t);
        stage_tile<TBN>(Bb, krow, kb0, Bs[b], t);
        if (SPLIT) {
            stage_tile<TBM>(Alb, krow, kb0, As[b] + TBM * BK, t);
            stage_tile<TBN>(Blb, krow, kb0, Bs[b] + TBN * BK, t);
        }
    };

    stage_all(0, koff);
    __syncthreads();
    int cur = 0;

    for (int k0 = koff; k0 < koff + klen; k0 += BK) {
        if (k0 + BK < koff + klen) stage_all(cur ^ 1, k0 + BK);  // prefetch in flight
        const u16* Ac = As[cur];
        const u16* Bc = Bs[cur];
        bf16x8 fa[FM], fb[FN], fal[FM], fbl[FN];
#pragma unroll
        for (int i = 0; i < FM; i++) {
            int a = swz((wr * WM + i * 16 + ro) * 64 + ko);
            fa[i] = *reinterpret_cast<const bf16x8*>((const char*)Ac + a);
            if (SPLIT)
                fal[i] = *reinterpret_cast<const bf16x8*>((const char*)(Ac + TBM * BK) + a);
        }
#pragma unroll
        for (int j = 0; j < FN; j++) {
            int a = swz((wc * WN + j * 16 + ro) * 64 + ko);
            fb[j] = *reinterpret_cast<const bf16x8*>((const char*)Bc + a);
            if (SPLIT)
                fbl[j] = *reinterpret_cast<const bf16x8*>((const char*)(Bc + TBN * BK) + a);
        }
#pragma unroll
        for (int i = 0; i < FM; i++)
#pragma unroll
            for (int j = 0; j < FN; j++) {
                acc[i][j] = __builtin_amdgcn_mfma_f32_16x16x32_bf16(fa[i], fb[j],
                                                                    acc[i][j], 0, 0, 0);
                if (SPLIT) {
                    acc[i][j] = __builtin_amdgcn_mfma_f32_16x16x32_bf16(fa[i], fbl[j],
                                                                        acc[i][j], 0, 0, 0);
                    acc[i][j] = __builtin_amdgcn_mfma_f32_16x16x32_bf16(fal[i], fb[j],
                                                                        acc[i][j], 0, 0, 0);
                }
            }
        __syncthreads();
        cur ^= 1;
    }

#pragma unroll
    for (int i = 0; i < FM; i++)
#pragma unroll
        for (int j = 0; j < FN; j++) {
            int col = n0 + wc * WN + j * 16 + (lane & 15);
            int rbase = m0 + wr * WM + i * 16 + (lane >> 4) * 4;
#pragma unroll
            for (int r = 0; r < 4; r++) {
                int row = rbase + r;
                float v = acc[i][j][r];
                size_t off = (size_t)row * N + col;
                if (EPI == 0) {
                    ((float*)Cout)[off] = v;
                } else if (EPI == 1) {
                    float s = v / (1.f + __expf(-v));
                    ((u16*)Cout)[off] = f2bf(s);
                } else {
                    if (KCHUNKS == 1 || blockIdx.z == 0)
                        ((float*)Cout)[off] = v + ext[off];
                    else
                        ((float*)Cout2)[off] = v;
                }
            }
        }
}

// Rank of value v (lane l) among 64 values in LDS, JAX top_k tie order.
__device__ __forceinline__ int rank64(const float* base, float v, int l) {
    const float4* gv = reinterpret_cast<const float4*>(base);
    int rank = 0;
#pragma unroll
    for (int n = 0; n < 16; n++) {
        float4 o = gv[n];
        int b = n * 4;
        rank += (o.x > v) || (o.x == v && (b + 0) < l);
        rank += (o.y > v) || (o.y == v && (b + 1) < l);
        rank += (o.z > v) || (o.z == v && (b + 2) < l);
        rank += (o.w > v) || (o.w == v && (b + 3) < l);
    }
    return rank;
}

// Per-token router: loads precomputed sims (= hid @ Weff^T), rank-based
// top-8 per (p,h) group, rank-based cartesian top-8 per head, softmax gates.
__global__ __launch_bounds__(512) void router(
    const float* __restrict__ Simb,
    int* __restrict__ sidx_g, float* __restrict__ gate_g) {
    __shared__ float sims[QDIM];
    __shared__ float topv[8][TOPK];
    __shared__ int topi[8][TOPK];
    __shared__ float pv[NHEADS][64];
    __shared__ float st8[NHEADS][TOPK];
    __shared__ int sid8[NHEADS][TOPK];

    const int tok = blockIdx.x;
    const int tid = threadIdx.x;
    const int w = tid >> 6, l = tid & 63;

    sims[tid] = Simb[(size_t)tok * QDIM + tid];
    __syncthreads();

    {
        float v = sims[w * 64 + l];
        int rank = rank64(sims + w * 64, v, l);
        if (rank < TOPK) { topv[w][rank] = v; topi[w][rank] = l; }
    }
    __syncthreads();

    if (w < NHEADS) {
        pv[w][l] = topv[w][l >> 3] + topv[4 + w][l & 7];
    }
    __syncthreads();

    if (w < NHEADS) {
        float v = pv[w][l];
        int rank = rank64(pv[w], v, l);
        if (rank < TOPK) {
            st8[w][rank] = v;
            sid8[w][rank] = topi[w][l >> 3] * NKEYS + topi[4 + w][l & 7];
        }
    }
    __syncthreads();

    if (tid < NHEADS * TOPK) {
        int h = tid >> 3, r = tid & 7;
        float m0 = st8[h][0];
        float s = 0.f;
#pragma unroll
        for (int i = 0; i < TOPK; i++) s += __expf(st8[h][i] - m0);
        size_t o = ((size_t)tok * NHEADS + h) * TOPK + r;
        sidx_g[o] = sid8[h][r];
        gate_g[o] = __expf(st8[h][r] - m0) / s;
    }
}

// Streaming expert gather, fp8-e4m3 tables: one token per 256-thread block.
__global__ __launch_bounds__(256) void expert_gather(
    const u16* __restrict__ hid_bf, const u32* __restrict__ de_f8,
    const u32* __restrict__ ue_f8, const int* __restrict__ sidx_g,
    const float* __restrict__ gate_g, float* __restrict__ expst) {
    __shared__ float wks[32];
    __shared__ int eids_s[32];

    const int tok = blockIdx.x;
    const int w = threadIdx.x >> 6, l = threadIdx.x & 63;

    {   // dot phase
        u16x8 hv[2];
        const u16* hrow = hid_bf + (size_t)tok * HDIM + l * 16;
        hv[0] = *reinterpret_cast<const u16x8*>(hrow);
        hv[1] = *reinterpret_cast<const u16x8*>(hrow + 8);
        float h16[16];
#pragma unroll
        for (int t2 = 0; t2 < 8; t2++) { h16[t2] = bf2f(hv[0][t2]); h16[8 + t2] = bf2f(hv[1][t2]); }
        int eid[8];
        float gt[8];
#pragma unroll
        for (int j = 0; j < 8; j++) {
            size_t o = (size_t)tok * 32 + w * 8 + j;
            eid[j] = sidx_g[o];
            gt[j] = gate_g[o];
        }
        u32x4 dv[8];
#pragma unroll
        for (int j = 0; j < 8; j++) {
            const u32x4* dr = reinterpret_cast<const u32x4*>(de_f8 + (size_t)eid[j] * 256 + l * 4);
            dv[j] = *dr;
        }
        float dot[8];
#pragma unroll
        for (int j = 0; j < 8; j++) {
            float s = 0.f;
#pragma unroll
            for (int w2 = 0; w2 < 4; w2++) {
                u32 word = dv[j][w2];
                s += h16[w2 * 4 + 0] * __builtin_amdgcn_cvt_f32_fp8(word, 0);
                s += h16[w2 * 4 + 1] * __builtin_amdgcn_cvt_f32_fp8(word, 1);
                s += h16[w2 * 4 + 2] * __builtin_amdgcn_cvt_f32_fp8(word, 2);
                s += h16[w2 * 4 + 3] * __builtin_amdgcn_cvt_f32_fp8(word, 3);
            }
            dot[j] = s;
        }
#pragma unroll
        for (int m = 32; m; m >>= 1)
#pragma unroll
            for (int j = 0; j < 8; j++) dot[j] += __shfl_xor(dot[j], m, 64);
#pragma unroll
        for (int j = 0; j < 8; j++)
            if (l == j) {
                float x = dot[j] * gt[j];
                wks[w * 8 + j] = x / (1.f + __expf(-x));
                eids_s[w * 8 + j] = eid[j];
            }
    }
    __syncthreads();

    {   // acc phase: wave w owns dims [w*256, (w+1)*256); 4 fp8 per lane
        float acc0 = 0.f, acc1 = 0.f, acc2 = 0.f, acc3 = 0.f;
        const u32* ubase = ue_f8 + w * 64 + l;
#pragma unroll
        for (int m = 0; m < 32; m++) {
            int e = eids_s[m];
            float wk = wks[m];
            u32 u = ubase[(size_t)e * 256];
            acc0 += wk * __builtin_amdgcn_cvt_f32_fp8(u, 0);
            acc1 += wk * __builtin_amdgcn_cvt_f32_fp8(u, 1);
            acc2 += wk * __builtin_amdgcn_cvt_f32_fp8(u, 2);
            acc3 += wk * __builtin_amdgcn_cvt_f32_fp8(u, 3);
        }
        float4 a4 = make_float4(acc0, acc1, acc2, acc3);
        *reinterpret_cast<float4*>(expst + (size_t)tok * HDIM + w * 256 + l * 4) = a4;
    }
}

extern "C" void kernel_launch(void* const* d_in, const int* in_sizes, int n_in,
                              void* d_out, int out_size, void* d_ws, size_t ws_size,
                              hipStream_t stream) {
    const float* hidden = (const float*)d_in[0];
    const float* W_up = (const float*)d_in[1];
    const float* W_down = (const float*)d_in[2];
    const float* W_q = (const float*)d_in[3];
    const float* keys = (const float*)d_in[4];
    const float* down_embed = (const float*)d_in[5];
    const float* up_embed = (const float*)d_in[6];
    float* out = (float*)d_out;

    char* ws = (char*)d_ws;
    size_t off = 0;
    auto alloc = [&](size_t bytes) {
        void* p = ws + off;
        off += (bytes + 255) & ~(size_t)255;
        return p;
    };
    u16* hid_hi = (u16*)alloc((size_t)TOKENS * HDIM * 2);
    // hid_lo (8.39 MB) + Simb (8.39 MB) are dead after router; the down-proj
    // K-chunk-1 partial (16.78 MB) overlays them.
    u16* hid_lo = (u16*)alloc((size_t)TOKENS * HDIM * 2);
    float* Simb = (float*)alloc((size_t)TOKENS * QDIM * 4);
    float* partial = (float*)hid_lo;
    u16* weff_hi = (u16*)alloc((size_t)QDIM * HDIM * 2);
    u16* weff_lo = (u16*)alloc((size_t)QDIM * HDIM * 2);
    u16* wup = (u16*)alloc((size_t)IDIM * HDIM * 2);
    u16* wdn = (u16*)alloc((size_t)HDIM * IDIM * 2);
    u16* act = (u16*)alloc((size_t)TOKENS * IDIM * 2);
    u32* de_f8 = (u32*)alloc((size_t)4096 * HDIM);
    u32* ue_f8 = (u32*)alloc((size_t)4096 * HDIM);
    float* expst = (float*)alloc((size_t)TOKENS * HDIM * 4);
    int* sidx_g = (int*)alloc((size_t)TOKENS * 32 * 4);
    float* gate_g = (float*)alloc((size_t)TOKENS * 32 * 4);

    cvt_all<<<(CVT_TOT + 255) / 256, 256, 0, stream>>>(
        hidden, W_up, W_down, down_embed, up_embed,
        hid_hi, hid_lo, wup, wdn, de_f8, ue_f8);
    weff_kernel<<<64, 256, 0, stream>>>(keys, W_q, weff_hi, weff_lo);

    dim3 blk(256);
    // sim projection (q-proj with keys folded in), split-bf16, 64x128 tile
    gemm_bt<0, 64, 128, true, 1><<<dim3(QDIM / 128, TOKENS / 64), blk, 0, stream>>>(
        hid_hi, hid_lo, weff_hi, weff_lo, Simb, nullptr, nullptr, TOKENS, QDIM, HDIM);

    router<<<TOKENS, 512, 0, stream>>>(Simb, sidx_g, gate_g);
    expert_gather<<<TOKENS, 256, 0, stream>>>(hid_hi, de_f8, ue_f8, sidx_g, gate_g, expst);

    // up proj: 128x128 tile, grid 1024
    gemm_bt<1, 128, 128, false, 1><<<dim3(IDIM / 128, TOKENS / 128), blk, 0, stream>>>(
        hid_hi, nullptr, wup, nullptr, act, nullptr, nullptr, TOKENS, IDIM, HDIM);
    // down proj: 128x64 tile, K-split x2 -> grid (16,32,2)=1024 blocks
    gemm_bt<2, 128, 64, false, 2><<<dim3(HDIM / 64, TOKENS / 128, 2), blk, 0, stream>>>(
        act, nullptr, wdn, nullptr, out, partial, expst, TOKENS, HDIM, IDIM);
    reduce_add<<<(TOKENS * HDIM / 4 + 255) / 256, 256, 0, stream>>>(out, partial,
                                                                    TOKENS * HDIM / 4);
}

// Round 9
// 222.744 us; speedup vs baseline: 2.3398x; 1.0590x over previous
//
#include <hip/hip_runtime.h>

typedef unsigned short u16;
typedef unsigned int u32;

#define TOKENS 4096   // B*T
#define HDIM 1024
#define IDIM 4096
#define NHEADS 4
#define NKEYS 64
#define TOPK 8
#define QDIM 512      // 2 * NHEADS * 64

typedef __bf16 bf16x8 __attribute__((ext_vector_type(8)));
typedef float  f32x4  __attribute__((ext_vector_type(4)));
typedef u16    u16x8  __attribute__((ext_vector_type(8)));
typedef u16    u16x4  __attribute__((ext_vector_type(4)));
typedef u32    u32x4  __attribute__((ext_vector_type(4)));

__device__ __forceinline__ u16 f2bf(float f) {
    u32 u = __float_as_uint(f);
    u += 0x7fffu + ((u >> 16) & 1u);   // RNE
    return (u16)(u >> 16);
}
__device__ __forceinline__ float bf2f(u16 h) { return __uint_as_float(((u32)h) << 16); }

// ---- fused fp32->bf16 / fp32->fp8 conversion over all tensors ----
#define H_N4   1048576   // TOKENS*HDIM/4   (hi+lo)
#define WUP_N4 1048576
#define WDN_N4 1048576
#define DE_N4  1048576
#define UE_N4  1048576
#define CVT_TOT (H_N4 + WUP_N4 + WDN_N4 + DE_N4 + UE_N4)

__device__ __forceinline__ void cvt1(const float* in, u16* hi, u16* lo, int i) {
    float4 v = reinterpret_cast<const float4*>(in)[i];
    float vf[4] = {v.x, v.y, v.z, v.w};
    ushort4 h;
    u16 hh[4];
#pragma unroll
    for (int j = 0; j < 4; j++) hh[j] = f2bf(vf[j]);
    h.x = hh[0]; h.y = hh[1]; h.z = hh[2]; h.w = hh[3];
    reinterpret_cast<ushort4*>(hi)[i] = h;
    if (lo) {
        ushort4 l4;
        u16 ll[4];
#pragma unroll
        for (int j = 0; j < 4; j++) ll[j] = f2bf(vf[j] - bf2f(hh[j]));
        l4.x = ll[0]; l4.y = ll[1]; l4.z = ll[2]; l4.w = ll[3];
        reinterpret_cast<ushort4*>(lo)[i] = l4;
    }
}

__device__ __forceinline__ void cvt1_f8(const float* in, u32* out8, int i) {
    float4 v = reinterpret_cast<const float4*>(in)[i];
    u32 w = __builtin_amdgcn_cvt_pk_fp8_f32(v.x, v.y, 0u, false);
    w = __builtin_amdgcn_cvt_pk_fp8_f32(v.z, v.w, w, true);
    out8[i] = w;
}

__global__ __launch_bounds__(256) void cvt_all(
    const float* __restrict__ hidden, const float* __restrict__ W_up,
    const float* __restrict__ W_down, const float* __restrict__ de,
    const float* __restrict__ ue,
    u16* __restrict__ hid_hi, u16* __restrict__ hid_lo,
    u16* __restrict__ wup, u16* __restrict__ wdn,
    u32* __restrict__ de_f8, u32* __restrict__ ue_f8) {
    int i = blockIdx.x * 256 + threadIdx.x;
    if (i >= CVT_TOT) return;
    if (i < H_N4) { cvt1(hidden, hid_hi, hid_lo, i); return; }
    i -= H_N4;
    if (i < WUP_N4) { cvt1(W_up, wup, nullptr, i); return; }
    i -= WUP_N4;
    if (i < WDN_N4) { cvt1(W_down, wdn, nullptr, i); return; }
    i -= WDN_N4;
    if (i < DE_N4) { cvt1_f8(de, de_f8, i); return; }
    i -= DE_N4;
    cvt1_f8(ue, ue_f8, i);
}

// Weff[(p*4+h)*64+k][d] = sum_n keys[h][k][p][n] * Wq[p*256+h*64+n][d],
// fp32 accumulate, split hi/lo bf16 output.
__global__ __launch_bounds__(256) void weff_kernel(
    const float* __restrict__ keys, const float* __restrict__ Wq,
    u16* __restrict__ weff_hi, u16* __restrict__ weff_lo) {
    __shared__ float kk[64][65];
    __shared__ float wq_s[64][128];

    const int g = blockIdx.x >> 3, ds = blockIdx.x & 7;
    const int p = g >> 2, h = g & 3;
    const int d0 = ds * 128;
    const int t = threadIdx.x;
    const int base = p * 256 + h * 64;

    {
        int k = t >> 2, part = t & 3;
        const float* krow = keys + (((size_t)(h * NKEYS + k) * 2 + p) * 64);
#pragma unroll
        for (int j = 0; j < 4; j++) {
            int n0 = part * 16 + j * 4;
            float4 v = *reinterpret_cast<const float4*>(krow + n0);
            kk[k][n0 + 0] = v.x; kk[k][n0 + 1] = v.y;
            kk[k][n0 + 2] = v.z; kk[k][n0 + 3] = v.w;
        }
    }
    {
        int n = t >> 2, dpart = t & 3;
        const float* wrow = Wq + (size_t)(base + n) * HDIM + d0;
#pragma unroll
        for (int j = 0; j < 8; j++) {
            int dd = dpart * 32 + j * 4;
            float4 v = *reinterpret_cast<const float4*>(wrow + dd);
            *reinterpret_cast<float4*>(&wq_s[n][dd]) = v;
        }
    }
    __syncthreads();

    const int k = t & 63, dq = t >> 6;
    float acc[32];
#pragma unroll
    for (int i = 0; i < 32; i++) acc[i] = 0.f;
    for (int n = 0; n < 64; n++) {
        float kv = kk[k][n];
        const float4* wrow = reinterpret_cast<const float4*>(&wq_s[n][dq * 32]);
#pragma unroll
        for (int j = 0; j < 8; j++) {
            float4 w4 = wrow[j];
            acc[j * 4 + 0] += kv * w4.x; acc[j * 4 + 1] += kv * w4.y;
            acc[j * 4 + 2] += kv * w4.z; acc[j * 4 + 3] += kv * w4.w;
        }
    }
    size_t ro = (size_t)(g * 64 + k) * HDIM + d0 + dq * 32;
#pragma unroll
    for (int j = 0; j < 8; j++) {
        ushort4 hh, ll;
        u16 hv[4], lv[4];
#pragma unroll
        for (int i = 0; i < 4; i++) {
            float a = acc[j * 4 + i];
            hv[i] = f2bf(a);
            lv[i] = f2bf(a - bf2f(hv[i]));
        }
        hh.x = hv[0]; hh.y = hv[1]; hh.z = hv[2]; hh.w = hv[3];
        ll.x = lv[0]; ll.y = lv[1]; ll.z = lv[2]; ll.w = lv[3];
        *reinterpret_cast<ushort4*>(weff_hi + ro + j * 4) = hh;
        *reinterpret_cast<ushort4*>(weff_lo + ro + j * 4) = ll;
    }
}

// out += partial (after both K-chunks of down proj completed)
__global__ __launch_bounds__(256) void reduce_add(float* __restrict__ out,
                                                  const float* __restrict__ p, int n4) {
    int i = blockIdx.x * 256 + threadIdx.x;
    if (i >= n4) return;
    float4 a = reinterpret_cast<const float4*>(out)[i];
    float4 b = reinterpret_cast<const float4*>(p)[i];
    a.x += b.x; a.y += b.y; a.z += b.z; a.w += b.w;
    reinterpret_cast<float4*>(out)[i] = a;
}

__device__ __forceinline__ void gload16(const void* g, void* s) {
    auto gp = reinterpret_cast<const __attribute__((address_space(1))) u32*>(
        reinterpret_cast<uintptr_t>(g));
    auto sp = reinterpret_cast<__attribute__((address_space(3))) u32*>(
        reinterpret_cast<uintptr_t>(s));
    __builtin_amdgcn_global_load_lds(gp, sp, 16, 0, 0);
}

#define BK 32

// LDS tile layout: rows of 64B (32 bf16). Swizzle: 16B slot ^= (row>>1)&3.
// Verified R5: SQ_LDS_BANK_CONFLICT 4.2M -> 0.
__device__ __forceinline__ int swz(int a) { return a ^ (((a >> 7) & 3) << 4); }

template <int ROWS, int THREADS>
__device__ __forceinline__ void stage_tile(const u16* g, size_t krow_b, size_t kb0,
                                           u16* s, int t) {
#pragma unroll
    for (int rnd = 0; rnd < ROWS * 64 / (THREADS * 16); rnd++) {
        int o = t * 16 + rnd * THREADS * 16;
        int os = swz(o);
        int row = o >> 6, kb = os & 63;
        gload16((const char*)g + (size_t)row * krow_b + kb0 + kb, (char*)s + o);
    }
}

// C[M,N] = A[M,K]*B[N,K]^T (+ SPLIT: A_lo*B + A*B_lo), bf16 in, fp32 acc.
// 2-phase pipelined; wave grid WVM x WVN (THREADS = WVM*WVN*64).
// XSWZ: XCD-aware bijective bid remap within each z-slice (T1).
template <int EPI, int TBM, int TBN, int WVM, int WVN, bool SPLIT, int KCHUNKS, bool XSWZ>
__global__ __launch_bounds__(WVM * WVN * 64) void gemm_bt(
    const u16* __restrict__ A, const u16* __restrict__ Alo,
    const u16* __restrict__ B, const u16* __restrict__ Blo,
    void* __restrict__ Cout, void* __restrict__ Cout2,
    const float* __restrict__ ext, int M, int N, int K) {
    constexpr int THREADS = WVM * WVN * 64;
    constexpr int NS = SPLIT ? 2 : 1;
    constexpr int WM = TBM / WVM, WN = TBN / WVN;
    constexpr int FM = WM / 16, FN = WN / 16;
    constexpr int ASZ = NS * TBM * BK;
    constexpr int BSZ = NS * TBN * BK;
    __shared__ u16 As[2][ASZ];
    __shared__ u16 Bs[2][BSZ];
    const int t = threadIdx.x;
    const int lane = t & 63;
    const int wave = t >> 6;
    const int wr = wave / WVN, wc = wave % WVN;

    int bx = blockIdx.x, by = blockIdx.y;
    if (XSWZ) {
        int gx = gridDim.x, gy = gridDim.y;
        int n = gx * gy;                 // must be divisible by 8
        int bid = by * gx + bx;
        int q = n >> 3;
        bid = (bid & 7) * q + (bid >> 3);
        bx = bid % gx; by = bid / gx;
    }
    const int m0 = by * TBM;
    const int n0 = bx * TBN;
    const int klen = K / KCHUNKS;
    const int koff = (KCHUNKS > 1) ? blockIdx.z * klen : 0;

    f32x4 acc[FM][FN];
#pragma unroll
    for (int i = 0; i < FM; i++)
#pragma unroll
        for (int j = 0; j < FN; j++) acc[i][j] = (f32x4){0.f, 0.f, 0.f, 0.f};

    const size_t krow = (size_t)K * 2;  // bytes per row
    const int ro = lane & 15;
    const int ko = (lane >> 4) * 16;  // byte offset into 64B row

    const u16* Ab = A + (size_t)m0 * K;
    const u16* Bb = B + (size_t)n0 * K;
    const u16* Alb = SPLIT ? Alo + (size_t)m0 * K : nullptr;
    const u16* Blb = SPLIT ? Blo + (size_t)n0 * K : nullptr;

    auto stage_all = [&](int b, int k0) {
        size_t kb0 = (size_t)k0 * 2;
        stage_tile<TBM, THREADS>(Ab, krow, kb0, As[b], t);
        stage_tile<TBN, THREADS>(Bb, krow, kb0, Bs[b], t);
        if (SPLIT) {
            stage_tile<TBM, THREADS>(Alb, krow, kb0, As[b] + TBM * BK, t);
            stage_tile<TBN, THREADS>(Blb, krow, kb0, Bs[b] + TBN * BK, t);
        }
    };

    stage_all(0, koff);
    __syncthreads();
    int cur = 0;

    for (int k0 = koff; k0 < koff + klen; k0 += BK) {
        if (k0 + BK < koff + klen) stage_all(cur ^ 1, k0 + BK);  // prefetch in flight
        const u16* Ac = As[cur];
        const u16* Bc = Bs[cur];
        bf16x8 fa[FM], fb[FN], fal[FM], fbl[FN];
#pragma unroll
        for (int i = 0; i < FM; i++) {
            int a = swz((wr * WM + i * 16 + ro) * 64 + ko);
            fa[i] = *reinterpret_cast<const bf16x8*>((const char*)Ac + a);
            if (SPLIT)
                fal[i] = *reinterpret_cast<const bf16x8*>((const char*)(Ac + TBM * BK) + a);
        }
#pragma unroll
        for (int j = 0; j < FN; j++) {
            int a = swz((wc * WN + j * 16 + ro) * 64 + ko);
            fb[j] = *reinterpret_cast<const bf16x8*>((const char*)Bc + a);
            if (SPLIT)
                fbl[j] = *reinterpret_cast<const bf16x8*>((const char*)(Bc + TBN * BK) + a);
        }
#pragma unroll
        for (int i = 0; i < FM; i++)
#pragma unroll
            for (int j = 0; j < FN; j++) {
                acc[i][j] = __builtin_amdgcn_mfma_f32_16x16x32_bf16(fa[i], fb[j],
                                                                    acc[i][j], 0, 0, 0);
                if (SPLIT) {
                    acc[i][j] = __builtin_amdgcn_mfma_f32_16x16x32_bf16(fa[i], fbl[j],
                                                                        acc[i][j], 0, 0, 0);
                    acc[i][j] = __builtin_amdgcn_mfma_f32_16x16x32_bf16(fal[i], fb[j],
                                                                        acc[i][j], 0, 0, 0);
                }
            }
        __syncthreads();
        cur ^= 1;
    }

#pragma unroll
    for (int i = 0; i < FM; i++)
#pragma unroll
        for (int j = 0; j < FN; j++) {
            int col = n0 + wc * WN + j * 16 + (lane & 15);
            int rbase = m0 + wr * WM + i * 16 + (lane >> 4) * 4;
#pragma unroll
            for (int r = 0; r < 4; r++) {
                int row = rbase + r;
                float v = acc[i][j][r];
                size_t off = (size_t)row * N + col;
                if (EPI == 0) {
                    ((float*)Cout)[off] = v;
                } else if (EPI == 1) {
                    float s = v / (1.f + __expf(-v));
                    ((u16*)Cout)[off] = f2bf(s);
                } else {
                    if (KCHUNKS == 1 || blockIdx.z == 0)
                        ((float*)Cout)[off] = v + ext[off];
                    else
                        ((float*)Cout2)[off] = v;
                }
            }
        }
}

// Rank of value v (lane l) among 64 values in LDS, JAX top_k tie order.
__device__ __forceinline__ int rank64(const float* base, float v, int l) {
    const float4* gv = reinterpret_cast<const float4*>(base);
    int rank = 0;
#pragma unroll
    for (int n = 0; n < 16; n++) {
        float4 o = gv[n];
        int b = n * 4;
        rank += (o.x > v) || (o.x == v && (b + 0) < l);
        rank += (o.y > v) || (o.y == v && (b + 1) < l);
        rank += (o.z > v) || (o.z == v && (b + 2) < l);
        rank += (o.w > v) || (o.w == v && (b + 3) < l);
    }
    return rank;
}

// Per-token router: loads precomputed sims (= hid @ Weff^T), rank-based
// top-8 per (p,h) group, rank-based cartesian top-8 per head, softmax gates.
__global__ __launch_bounds__(512) void router(
    const float* __restrict__ Simb,
    int* __restrict__ sidx_g, float* __restrict__ gate_g) {
    __shared__ float sims[QDIM];
    __shared__ float topv[8][TOPK];
    __shared__ int topi[8][TOPK];
    __shared__ float pv[NHEADS][64];
    __shared__ float st8[NHEADS][TOPK];
    __shared__ int sid8[NHEADS][TOPK];

    const int tok = blockIdx.x;
    const int tid = threadIdx.x;
    const int w = tid >> 6, l = tid & 63;

    sims[tid] = Simb[(size_t)tok * QDIM + tid];
    __syncthreads();

    {
        float v = sims[w * 64 + l];
        int rank = rank64(sims + w * 64, v, l);
        if (rank < TOPK) { topv[w][rank] = v; topi[w][rank] = l; }
    }
    __syncthreads();

    if (w < NHEADS) {
        pv[w][l] = topv[w][l >> 3] + topv[4 + w][l & 7];
    }
    __syncthreads();

    if (w < NHEADS) {
        float v = pv[w][l];
        int rank = rank64(pv[w], v, l);
        if (rank < TOPK) {
            st8[w][rank] = v;
            sid8[w][rank] = topi[w][l >> 3] * NKEYS + topi[4 + w][l & 7];
        }
    }
    __syncthreads();

    if (tid < NHEADS * TOPK) {
        int h = tid >> 3, r = tid & 7;
        float m0 = st8[h][0];
        float s = 0.f;
#pragma unroll
        for (int i = 0; i < TOPK; i++) s += __expf(st8[h][i] - m0);
        size_t o = ((size_t)tok * NHEADS + h) * TOPK + r;
        sidx_g[o] = sid8[h][r];
        gate_g[o] = __expf(st8[h][r] - m0) / s;
    }
}

// Streaming expert gather, fp8-e4m3 tables: one token per 256-thread block.
__global__ __launch_bounds__(256) void expert_gather(
    const u16* __restrict__ hid_bf, const u32* __restrict__ de_f8,
    const u32* __restrict__ ue_f8, const int* __restrict__ sidx_g,
    const float* __restrict__ gate_g, float* __restrict__ expst) {
    __shared__ float wks[32];
    __shared__ int eids_s[32];

    const int tok = blockIdx.x;
    const int w = threadIdx.x >> 6, l = threadIdx.x & 63;

    {   // dot phase
        u16x8 hv[2];
        const u16* hrow = hid_bf + (size_t)tok * HDIM + l * 16;
        hv[0] = *reinterpret_cast<const u16x8*>(hrow);
        hv[1] = *reinterpret_cast<const u16x8*>(hrow + 8);
        float h16[16];
#pragma unroll
        for (int t2 = 0; t2 < 8; t2++) { h16[t2] = bf2f(hv[0][t2]); h16[8 + t2] = bf2f(hv[1][t2]); }
        int eid[8];
        float gt[8];
#pragma unroll
        for (int j = 0; j < 8; j++) {
            size_t o = (size_t)tok * 32 + w * 8 + j;
            eid[j] = sidx_g[o];
            gt[j] = gate_g[o];
        }
        u32x4 dv[8];
#pragma unroll
        for (int j = 0; j < 8; j++) {
            const u32x4* dr = reinterpret_cast<const u32x4*>(de_f8 + (size_t)eid[j] * 256 + l * 4);
            dv[j] = *dr;
        }
        float dot[8];
#pragma unroll
        for (int j = 0; j < 8; j++) {
            float s = 0.f;
#pragma unroll
            for (int w2 = 0; w2 < 4; w2++) {
                u32 word = dv[j][w2];
                s += h16[w2 * 4 + 0] * __builtin_amdgcn_cvt_f32_fp8(word, 0);
                s += h16[w2 * 4 + 1] * __builtin_amdgcn_cvt_f32_fp8(word, 1);
                s += h16[w2 * 4 + 2] * __builtin_amdgcn_cvt_f32_fp8(word, 2);
                s += h16[w2 * 4 + 3] * __builtin_amdgcn_cvt_f32_fp8(word, 3);
            }
            dot[j] = s;
        }
#pragma unroll
        for (int m = 32; m; m >>= 1)
#pragma unroll
            for (int j = 0; j < 8; j++) dot[j] += __shfl_xor(dot[j], m, 64);
#pragma unroll
        for (int j = 0; j < 8; j++)
            if (l == j) {
                float x = dot[j] * gt[j];
                wks[w * 8 + j] = x / (1.f + __expf(-x));
                eids_s[w * 8 + j] = eid[j];
            }
    }
    __syncthreads();

    {   // acc phase: wave w owns dims [w*256, (w+1)*256); 4 fp8 per lane
        float acc0 = 0.f, acc1 = 0.f, acc2 = 0.f, acc3 = 0.f;
        const u32* ubase = ue_f8 + w * 64 + l;
#pragma unroll
        for (int m = 0; m < 32; m++) {
            int e = eids_s[m];
            float wk = wks[m];
            u32 u = ubase[(size_t)e * 256];
            acc0 += wk * __builtin_amdgcn_cvt_f32_fp8(u, 0);
            acc1 += wk * __builtin_amdgcn_cvt_f32_fp8(u, 1);
            acc2 += wk * __builtin_amdgcn_cvt_f32_fp8(u, 2);
            acc3 += wk * __builtin_amdgcn_cvt_f32_fp8(u, 3);
        }
        float4 a4 = make_float4(acc0, acc1, acc2, acc3);
        *reinterpret_cast<float4*>(expst + (size_t)tok * HDIM + w * 256 + l * 4) = a4;
    }
}

extern "C" void kernel_launch(void* const* d_in, const int* in_sizes, int n_in,
                              void* d_out, int out_size, void* d_ws, size_t ws_size,
                              hipStream_t stream) {
    const float* hidden = (const float*)d_in[0];
    const float* W_up = (const float*)d_in[1];
    const float* W_down = (const float*)d_in[2];
    const float* W_q = (const float*)d_in[3];
    const float* keys = (const float*)d_in[4];
    const float* down_embed = (const float*)d_in[5];
    const float* up_embed = (const float*)d_in[6];
    float* out = (float*)d_out;

    char* ws = (char*)d_ws;
    size_t off = 0;
    auto alloc = [&](size_t bytes) {
        void* p = ws + off;
        off += (bytes + 255) & ~(size_t)255;
        return p;
    };
    u16* hid_hi = (u16*)alloc((size_t)TOKENS * HDIM * 2);
    // hid_lo (8.39 MB) + Simb (8.39 MB) are dead after router; the down-proj
    // K-chunk-1 partial (16.78 MB) overlays them.
    u16* hid_lo = (u16*)alloc((size_t)TOKENS * HDIM * 2);
    float* Simb = (float*)alloc((size_t)TOKENS * QDIM * 4);
    float* partial = (float*)hid_lo;
    u16* weff_hi = (u16*)alloc((size_t)QDIM * HDIM * 2);
    u16* weff_lo = (u16*)alloc((size_t)QDIM * HDIM * 2);
    u16* wup = (u16*)alloc((size_t)IDIM * HDIM * 2);
    u16* wdn = (u16*)alloc((size_t)HDIM * IDIM * 2);
    u16* act = (u16*)alloc((size_t)TOKENS * IDIM * 2);
    u32* de_f8 = (u32*)alloc((size_t)4096 * HDIM);
    u32* ue_f8 = (u32*)alloc((size_t)4096 * HDIM);
    float* expst = (float*)alloc((size_t)TOKENS * HDIM * 4);
    int* sidx_g = (int*)alloc((size_t)TOKENS * 32 * 4);
    float* gate_g = (float*)alloc((size_t)TOKENS * 32 * 4);

    cvt_all<<<(CVT_TOT + 255) / 256, 256, 0, stream>>>(
        hidden, W_up, W_down, down_embed, up_embed,
        hid_hi, hid_lo, wup, wdn, de_f8, ue_f8);
    weff_kernel<<<64, 256, 0, stream>>>(keys, W_q, weff_hi, weff_lo);

    // sim projection (q-proj with keys folded in), split-bf16, 64x128 tile
    gemm_bt<0, 64, 128, 2, 2, true, 1, false>
        <<<dim3(QDIM / 128, TOKENS / 64), 256, 0, stream>>>(
        hid_hi, hid_lo, weff_hi, weff_lo, Simb, nullptr, nullptr, TOKENS, QDIM, HDIM);

    router<<<TOKENS, 512, 0, stream>>>(Simb, sidx_g, gate_g);
    expert_gather<<<TOKENS, 256, 0, stream>>>(hid_hi, de_f8, ue_f8, sidx_g, gate_g, expst);

    // up proj: 256x128 tile, 8 waves, grid (32,16)=512, XCD-swizzled
    gemm_bt<1, 256, 128, 4, 2, false, 1, true>
        <<<dim3(IDIM / 128, TOKENS / 256), 512, 0, stream>>>(
        hid_hi, nullptr, wup, nullptr, act, nullptr, nullptr, TOKENS, IDIM, HDIM);
    // down proj: 128x128 tile, K-split x2 -> grid (8,32,2)=512, XCD-swizzled
    gemm_bt<2, 128, 128, 2, 2, false, 2, true>
        <<<dim3(HDIM / 128, TOKENS / 128, 2), 256, 0, stream>>>(
        act, nullptr, wdn, nullptr, out, partial, expst, TOKENS, HDIM, IDIM);
    reduce_add<<<(TOKENS * HDIM / 4 + 255) / 256, 256, 0, stream>>>(out, partial,
                                                                    TOKENS * HDIM / 4);
}